// Round 5
// baseline (2493.908 us; speedup 1.0000x reference)
//
#include <hip/hip_runtime.h>

#define NB   16
#define NPT  4096
#define CINF 64
#define COUTF 128
#define MC   1024
#define KG   64
#define PTOT (NB*KG*MC)   /* 1048576 */

typedef unsigned short u16;
typedef unsigned int   u32;
typedef unsigned long long u64;

static __device__ __forceinline__ float blv(u16 v){ return __uint_as_float(((u32)v) << 16); }
static __device__ __forceinline__ u16 f2b(float f){
  u32 x = __float_as_uint(f);
  return (u16)((x + 0x7fffu + ((x >> 16) & 1u)) >> 16);
}

template<bool BF> struct io;
template<> struct io<true>{
  static __device__ __forceinline__ float ld(const void* p, size_t i){ return blv(((const u16*)p)[i]); }
  static __device__ __forceinline__ void st(void* p, size_t i, float v){ ((u16*)p)[i] = f2b(v); }
};
template<> struct io<false>{
  static __device__ __forceinline__ float ld(const void* p, size_t i){ return ((const float*)p)[i]; }
  static __device__ __forceinline__ void st(void* p, size_t i, float v){ ((float*)p)[i] = v; }
};

template<bool BF>
static __device__ __forceinline__ float4 ldw4(const void* w, int idx){
  if constexpr (BF) {
    ushort4 u = *(const ushort4*)((const u16*)w + idx);
    return make_float4(blv(u.x), blv(u.y), blv(u.z), blv(u.w));
  } else return *(const float4*)((const float*)w + idx);
}
template<bool BF>
static __device__ __forceinline__ void ldw8(const void* w, int idx, float4& a, float4& b){
  if constexpr (BF) {
    ushort4 u0 = *(const ushort4*)((const u16*)w + idx);
    ushort4 u1 = *(const ushort4*)((const u16*)w + idx + 4);
    a = make_float4(blv(u0.x), blv(u0.y), blv(u0.z), blv(u0.w));
    b = make_float4(blv(u1.x), blv(u1.y), blv(u1.z), blv(u1.w));
  } else {
    a = *(const float4*)((const float*)w + idx);
    b = *(const float4*)((const float*)w + idx + 4);
  }
}

// ---------------------------------------------------------------- detector + stats zero
__global__ __launch_bounds__(256) void detect_kernel(const void* pts, int* flagp, double* dstats)
{
  const int t = threadIdx.x;
  if (t < 64) {
    u32 w = ((const u32*)pts)[t];
    u64 m = __ballot((w & 0xFFFFu) < 0x4000u);
    if (t == 0) *flagp = (m == ~0ull) ? 1 : 0;
  }
  dstats[t] = 0.0;
}

// ---------------------------------------------------------------- FPS (1024 thr) + fused transpose
template<bool BF>
static __device__ void fps_body(const void* pts, float* __restrict__ centw, void* out,
                                float* lx, float* ly, float* lz, u64 (*red)[16])
{
  const int t = threadIdx.x, b = blockIdx.x;
  const size_t pbase = (size_t)b*3*NPT;
  for (int i = t; i < NPT; i += 1024) {
    lx[i] = io<BF>::ld(pts, pbase + i);
    ly[i] = io<BF>::ld(pts, pbase + NPT + i);
    lz[i] = io<BF>::ld(pts, pbase + 2*NPT + i);
  }
  __syncthreads();
  float qx[4],qy[4],qz[4],dd[4];
  const int base = t*4;
  #pragma unroll
  for (int j=0;j<4;++j){ qx[j]=lx[base+j]; qy[j]=ly[base+j]; qz[j]=lz[base+j]; dd[j]=1e10f; }
  int last = 0;
  const int lane = t & 63, wv = t >> 6;
  for (int it = 0; it < MC; ++it) {
    float cx = lx[last], cy = ly[last], cz = lz[last];
    if (t < 3) {
      float v = (t==0)?cx:((t==1)?cy:cz);
      centw[((size_t)b*MC + it)*3 + t] = v;
      io<BF>::st(out, (size_t)b*3*MC + (size_t)it*3 + t, v);
    }
    float bv = -1.f; int bi = base;
    #pragma unroll
    for (int j=0;j<4;++j) {
      float dx = __fsub_rn(qx[j], cx);
      float dy = __fsub_rn(qy[j], cy);
      float dz = __fsub_rn(qz[j], cz);
      float d  = __fadd_rn(__fadd_rn(__fmul_rn(dx,dx), __fmul_rn(dy,dy)), __fmul_rn(dz,dz));
      float nd = fminf(dd[j], d);
      dd[j] = nd;
      if (nd > bv) { bv = nd; bi = base + j; }   // strict >, ascending j => first max
    }
    u64 key = ((u64)__float_as_uint(bv) << 32) | (u32)(~bi);
    #pragma unroll
    for (int off = 32; off > 0; off >>= 1) {
      u64 o = __shfl_xor(key, off, 64);
      if (o > key) key = o;
    }
    if (lane == 0) red[it & 1][wv] = key;
    __syncthreads();
    u64 k0 = red[it & 1][0];
    #pragma unroll
    for (int i = 1; i < 16; ++i) { u64 ki = red[it & 1][i]; if (ki > k0) k0 = ki; }
    last = (int)(~(u32)k0);
  }
}

template<bool BF>
static __device__ void transpose_body(const void* feats, float* __restrict__ ftp)
{
  const int idx = (blockIdx.x - NB)*1024 + threadIdx.x;   // B*N total
  const int b = idx >> 12, n = idx & (NPT-1);
  const size_t base = (size_t)b*CINF*NPT + n;
  float* o = ftp + (size_t)idx*CINF;
  #pragma unroll
  for (int c = 0; c < CINF; c += 4) {
    float4 v;
    v.x = io<BF>::ld(feats, base + (size_t)(c+0)*NPT);
    v.y = io<BF>::ld(feats, base + (size_t)(c+1)*NPT);
    v.z = io<BF>::ld(feats, base + (size_t)(c+2)*NPT);
    v.w = io<BF>::ld(feats, base + (size_t)(c+3)*NPT);
    *(float4*)(o + c) = v;
  }
}

__global__ __launch_bounds__(1024) void fps_tr_kernel(const void* pts, const void* feats,
    float* centw, float* ftp, void* out, const int* flagp)
{
  __shared__ float lx[NPT], ly[NPT], lz[NPT];
  __shared__ u64 red[2][16];
  if (blockIdx.x < NB) {
    if (*flagp) fps_body<true >(pts, centw, out, lx, ly, lz, red);
    else        fps_body<false>(pts, centw, out, lx, ly, lz, red);
  } else {
    if (*flagp) transpose_body<true >(feats, ftp);
    else        transpose_body<false>(feats, ftp);
  }
}

// ---------------------------------------------------------------- ball query
template<bool BF>
static __device__ void ballq_body(const void* pts, const float* __restrict__ centw,
                                  int* __restrict__ gidx)
{
  const int lane = threadIdx.x & 63;
  const int g = blockIdx.x*4 + (threadIdx.x >> 6);
  const int b = g >> 10;
  const size_t pbase = (size_t)b*3*NPT;
  const float cx = centw[(size_t)g*3+0], cy = centw[(size_t)g*3+1], cz = centw[(size_t)g*3+2];
  int* gout = gidx + (size_t)g*KG;
  int taken = 0, idx0 = 0;
  for (int s = 0; s < NPT; s += 64) {
    int n = s + lane;
    float dx = __fsub_rn(cx, io<BF>::ld(pts, pbase + n));
    float dy = __fsub_rn(cy, io<BF>::ld(pts, pbase + NPT + n));
    float dz = __fsub_rn(cz, io<BF>::ld(pts, pbase + 2*NPT + n));
    float d2 = __fadd_rn(__fadd_rn(__fmul_rn(dx,dx), __fmul_rn(dy,dy)), __fmul_rn(dz,dz));
    u64 mask = __ballot(d2 <= 0.04f);
    if (mask) {
      if (taken == 0) idx0 = s + __ffsll((long long)mask) - 1;
      bool win = (mask >> lane) & 1;
      int pos = taken + __popcll(mask & ((1ull << lane) - 1ull));
      if (win && pos < KG) gout[pos] = n;
      taken += (int)__popcll(mask);
      if (taken >= KG) break;
    }
  }
  int cnt = taken < KG ? taken : KG;
  if (lane >= cnt) gout[lane] = idx0;
}

__global__ __launch_bounds__(256) void ballq_kernel(const void* pts, const float* centw,
                                                    int* gidx, const int* flagp)
{
  if (*flagp) ballq_body<true >(pts, centw, gidx);
  else        ballq_body<false>(pts, centw, gidx);
}

// ================================================================ LAYER-SPLIT PATH
// A[b,m,k,c] f32 tile in global ws. S1: gather+conv1->A+stats1. S2: bn1,relu,conv2 (in place)+stats2.
// S3: bn2,relu,conv3,max->out.

// ---------------- S1
template<bool BF>
__global__ __launch_bounds__(256) void s1_kernel(
    const void* pts, const float* __restrict__ ftp,
    const void* w1p, const void* b1p,
    const float* __restrict__ centw, const int* __restrict__ gidxp,
    double* __restrict__ dstats, float* __restrict__ A, const int* __restrict__ flagp)
{
  if ((*flagp != 0) != BF) return;
  __shared__ alignas(16) float Xs[4352];                       // [64][68]
  __shared__ alignas(16) unsigned char w1raw[BF ? 4352*2 : 4352*4];
  __shared__ alignas(16) float red[2176];
  __shared__ int gids[64];
  __shared__ float c3s[3];

  constexpr int TG = 8;
  const int t = threadIdx.x, lane = t & 63, wv = t >> 6;
  const int kq = lane >> 4, coq = lane & 15;
  const int co0 = coq * 4;
  const int k0  = wv*16 + kq*4;
  const int b   = blockIdx.x >> 7;
  const int m0  = (blockIdx.x & 127) * TG;

  // W1 permuted [c'][co]: c' 0..63 features, 64..66 coords, 67 zero
  for (int e = t; e < 4352; e += 256) {
    int cp = e >> 6, co = e & 63;
    int src = (cp < 64) ? (co*67 + cp + 3) : (cp < 67 ? co*67 + cp - 64 : -1);
    if constexpr (BF) ((u16*)w1raw)[e]   = (src >= 0) ? ((const u16*)w1p)[src]   : (u16)0;
    else              ((float*)w1raw)[e] = (src >= 0) ? ((const float*)w1p)[src] : 0.f;
  }
  float b1v[4];
  #pragma unroll
  for (int j=0;j<4;++j) b1v[j] = io<BF>::ld(b1p, co0+j);
  float run_s = 0.f, run_q = 0.f;
  __syncthreads();

  for (int mi = 0; mi < TG; ++mi) {
    const int m = m0 + mi;
    const size_t g = (size_t)b*MC + m;
    if (t < 64) gids[t] = gidxp[g*KG + t];
    if (t < 3)  c3s[t]  = centw[g*3 + t];
    __syncthreads();
    {
      const int gi = gids[lane];
      float* xrow = Xs + lane*68;
      const float* fp = ftp + ((size_t)b*NPT + gi)*CINF + wv*16;
      float4 v0 = ((const float4*)fp)[0], v1 = ((const float4*)fp)[1];
      float4 v2 = ((const float4*)fp)[2], v3 = ((const float4*)fp)[3];
      float4* d = (float4*)(xrow + wv*16);
      d[0]=v0; d[1]=v1; d[2]=v2; d[3]=v3;
      if (wv == 0) {
        const size_t pbase = (size_t)b*3*NPT;
        xrow[64] = __fsub_rn(io<BF>::ld(pts, pbase + gi),         c3s[0]);
        xrow[65] = __fsub_rn(io<BF>::ld(pts, pbase + NPT + gi),   c3s[1]);
        xrow[66] = __fsub_rn(io<BF>::ld(pts, pbase + 2*NPT + gi), c3s[2]);
        xrow[67] = 0.f;
      }
    }
    __syncthreads();
    float acc[4][4];
    #pragma unroll
    for (int r=0;r<4;++r){
      #pragma unroll
      for (int j=0;j<4;++j) acc[r][j] = b1v[j];
    }
    {
      const float* xb = Xs + (size_t)k0*68;
      for (int c4 = 0; c4 < 17; ++c4) {
        float4 xv[4], wr[4];
        #pragma unroll
        for (int r=0;r<4;++r) xv[r] = *(const float4*)(xb + r*68 + c4*4);
        #pragma unroll
        for (int q=0;q<4;++q) wr[q] = ldw4<BF>(w1raw, (c4*4+q)*64 + co0);
        #pragma unroll
        for (int q=0;q<4;++q){
          const float* w = (const float*)&wr[q];
          #pragma unroll
          for (int r=0;r<4;++r){
            const float x = ((const float*)&xv[r])[q];
            #pragma unroll
            for (int j=0;j<4;++j) acc[r][j] = fmaf(x, w[j], acc[r][j]);
          }
        }
      }
    }
    // write A + stats
    {
      float* Ag = A + g*4096;
      #pragma unroll
      for (int r=0;r<4;++r)
        *(float4*)(Ag + (size_t)(k0+r)*64 + co0) = make_float4(acc[r][0],acc[r][1],acc[r][2],acc[r][3]);
    }
    #pragma unroll
    for (int j=0;j<4;++j){
      float s  = (acc[0][j]+acc[1][j]) + (acc[2][j]+acc[3][j]);
      float q2 = fmaf(acc[0][j],acc[0][j], fmaf(acc[1][j],acc[1][j],
                 fmaf(acc[2][j],acc[2][j], acc[3][j]*acc[3][j])));
      red[(co0+j)*17 + wv*4 + kq] = s;
      red[1088 + (co0+j)*17 + wv*4 + kq] = q2;
    }
    __syncthreads();
    if (t < 64) {
      const float* r1 = red + t*17; const float* r2 = red + 1088 + t*17;
      float s=0.f, q=0.f;
      #pragma unroll
      for (int i=0;i<16;++i){ s += r1[i]; q += r2[i]; }
      run_s += s; run_q += q;
    }
  }
  if (t < 64) {
    atomicAdd(&dstats[lane],      (double)run_s);
    atomicAdd(&dstats[64 + lane], (double)run_q);
  }
}

// ---------------- S2 (in-place A update)
template<bool BF>
__global__ __launch_bounds__(256) void s2_kernel(
    const void* w2p, const void* b2p,
    const float* __restrict__ fstats, double* __restrict__ dstats,
    float* __restrict__ A, const int* __restrict__ flagp)
{
  if ((*flagp != 0) != BF) return;
  __shared__ alignas(16) float z1[4352];
  __shared__ alignas(16) unsigned char w2raw[BF ? 4096*2 : 4096*4];
  __shared__ alignas(16) float red[2176];
  __shared__ float scsh[128];

  constexpr int TG = 8;
  const int t = threadIdx.x, lane = t & 63, wv = t >> 6;
  const int kq = lane >> 4, coq = lane & 15;
  const int co0 = coq * 4;
  const int k0  = wv*16 + kq*4;
  const int b   = blockIdx.x >> 7;
  const int m0  = (blockIdx.x & 127) * TG;

  for (int e = t; e < 4096; e += 256) {
    int src = (e & 63)*64 + (e >> 6);
    if constexpr (BF) ((u16*)w2raw)[e] = ((const u16*)w2p)[src];
    else              ((float*)w2raw)[e] = ((const float*)w2p)[src];
  }
  if (t < 128) scsh[t] = fstats[t];   // sc1[0..63], sh1[64..127]
  float b2v[4];
  #pragma unroll
  for (int j=0;j<4;++j) b2v[j] = io<BF>::ld(b2p, co0+j);
  __syncthreads();
  const int c0 = (t*4) & 63;
  float scr[4], shr[4];
  #pragma unroll
  for (int j=0;j<4;++j){ scr[j] = scsh[c0+j]; shr[j] = scsh[64+c0+j]; }
  float run_s = 0.f, run_q = 0.f;

  for (int mi = 0; mi < TG; ++mi) {
    const size_t g = (size_t)b*MC + (m0 + mi);
    float* Ag = A + g*4096;
    #pragma unroll
    for (int u=0;u<4;++u){
      const int e = u*1024 + t*4;
      float4 v = *(const float4*)(Ag + e);
      const int row = e >> 6;
      float4 z;
      z.x = fmaxf(0.f, fmaf(v.x, scr[0], shr[0]));
      z.y = fmaxf(0.f, fmaf(v.y, scr[1], shr[1]));
      z.z = fmaxf(0.f, fmaf(v.z, scr[2], shr[2]));
      z.w = fmaxf(0.f, fmaf(v.w, scr[3], shr[3]));
      *(float4*)(z1 + (size_t)row*68 + c0) = z;
    }
    __syncthreads();
    float acc2[4][4];
    #pragma unroll
    for (int r=0;r<4;++r){
      #pragma unroll
      for (int j=0;j<4;++j) acc2[r][j] = b2v[j];
    }
    {
      const float* zb = z1 + (size_t)k0*68;
      for (int c4 = 0; c4 < 16; ++c4) {
        float4 xv[4], wr[4];
        #pragma unroll
        for (int r=0;r<4;++r) xv[r] = *(const float4*)(zb + r*68 + c4*4);
        #pragma unroll
        for (int q=0;q<4;++q) wr[q] = ldw4<BF>(w2raw, (c4*4+q)*64 + co0);
        #pragma unroll
        for (int q=0;q<4;++q){
          const float* w = (const float*)&wr[q];
          #pragma unroll
          for (int r=0;r<4;++r){
            const float x = ((const float*)&xv[r])[q];
            #pragma unroll
            for (int j=0;j<4;++j) acc2[r][j] = fmaf(x, w[j], acc2[r][j]);
          }
        }
      }
    }
    #pragma unroll
    for (int r=0;r<4;++r)
      *(float4*)(Ag + (size_t)(k0+r)*64 + co0) = make_float4(acc2[r][0],acc2[r][1],acc2[r][2],acc2[r][3]);
    #pragma unroll
    for (int j=0;j<4;++j){
      float s  = (acc2[0][j]+acc2[1][j]) + (acc2[2][j]+acc2[3][j]);
      float q2 = fmaf(acc2[0][j],acc2[0][j], fmaf(acc2[1][j],acc2[1][j],
                 fmaf(acc2[2][j],acc2[2][j], acc2[3][j]*acc2[3][j])));
      red[(co0+j)*17 + wv*4 + kq] = s;
      red[1088 + (co0+j)*17 + wv*4 + kq] = q2;
    }
    __syncthreads();
    if (t < 64) {
      const float* r1 = red + t*17; const float* r2 = red + 1088 + t*17;
      float s=0.f, q=0.f;
      #pragma unroll
      for (int i=0;i<16;++i){ s += r1[i]; q += r2[i]; }
      run_s += s; run_q += q;
    }
  }
  if (t < 64) {
    atomicAdd(&dstats[128 + lane], (double)run_s);
    atomicAdd(&dstats[192 + lane], (double)run_q);
  }
}

// ---------------- S3
template<bool BF>
__global__ __launch_bounds__(256) void s3_kernel(
    const void* w3p, const void* b3p,
    const float* __restrict__ fstats, const float* __restrict__ A,
    void* out, const int* __restrict__ flagp)
{
  if ((*flagp != 0) != BF) return;
  __shared__ alignas(16) float z2[4352];                   // redm overlays after conv3
  __shared__ alignas(16) unsigned char w3raw[BF ? 8192*2 : 8192*4];
  __shared__ float scsh[128];

  constexpr int TG = 8;
  const int t = threadIdx.x, lane = t & 63, wv = t >> 6;
  const int kq = lane >> 4, coq = lane & 15;
  const int co08 = coq * 8;
  const int k0  = wv*16 + kq*4;
  const int b   = blockIdx.x >> 7;
  const int m0  = (blockIdx.x & 127) * TG;

  for (int e = t; e < 8192; e += 256) {
    int src = (e & 127)*64 + (e >> 7);
    if constexpr (BF) ((u16*)w3raw)[e] = ((const u16*)w3p)[src];
    else              ((float*)w3raw)[e] = ((const float*)w3p)[src];
  }
  if (t < 128) scsh[t] = fstats[128 + t];   // sc2[0..63], sh2[64..127]
  float b3v[8];
  #pragma unroll
  for (int j=0;j<8;++j) b3v[j] = io<BF>::ld(b3p, co08+j);
  __syncthreads();
  const int c0 = (t*4) & 63;
  float scr[4], shr[4];
  #pragma unroll
  for (int j=0;j<4;++j){ scr[j] = scsh[c0+j]; shr[j] = scsh[64+c0+j]; }
  float outv[8];

  for (int mi = 0; mi < TG; ++mi) {
    const size_t g = (size_t)b*MC + (m0 + mi);
    const float* Ag = A + g*4096;
    #pragma unroll
    for (int u=0;u<4;++u){
      const int e = u*1024 + t*4;
      float4 v = *(const float4*)(Ag + e);
      const int row = e >> 6;
      float4 z;
      z.x = fmaxf(0.f, fmaf(v.x, scr[0], shr[0]));
      z.y = fmaxf(0.f, fmaf(v.y, scr[1], shr[1]));
      z.z = fmaxf(0.f, fmaf(v.z, scr[2], shr[2]));
      z.w = fmaxf(0.f, fmaf(v.w, scr[3], shr[3]));
      *(float4*)(z2 + (size_t)row*68 + c0) = z;
    }
    __syncthreads();
    float a3[4][8];
    #pragma unroll
    for (int r=0;r<4;++r){
      #pragma unroll
      for (int j=0;j<8;++j) a3[r][j] = b3v[j];
    }
    {
      const float* zb = z2 + (size_t)k0*68;
      for (int c4 = 0; c4 < 16; ++c4) {
        float4 xv[4], wr[4][2];
        #pragma unroll
        for (int r=0;r<4;++r) xv[r] = *(const float4*)(zb + r*68 + c4*4);
        #pragma unroll
        for (int q=0;q<4;++q) ldw8<BF>(w3raw, (c4*4+q)*128 + co08, wr[q][0], wr[q][1]);
        #pragma unroll
        for (int q=0;q<4;++q){
          const float* w = (const float*)&wr[q][0];
          #pragma unroll
          for (int r=0;r<4;++r){
            const float x = ((const float*)&xv[r])[q];
            #pragma unroll
            for (int j=0;j<8;++j) a3[r][j] = fmaf(x, w[j], a3[r][j]);
          }
        }
      }
    }
    __syncthreads();                 // all conv3 z2-reads done before redm overlays z2
    float* redm = z2;
    #pragma unroll
    for (int j=0;j<8;++j){
      float mv = fmaxf(fmaxf(a3[0][j],a3[1][j]), fmaxf(a3[2][j],a3[3][j]));
      redm[(co08+j)*17 + wv*4 + kq] = mv;
    }
    __syncthreads();
    if (t < 128) {
      const float* rr = redm + t*17;
      float s = rr[0];
      #pragma unroll
      for (int i=1;i<16;++i) s = fmaxf(s, rr[i]);
      outv[mi] = s;
    }
    __syncthreads();                 // redm reads done before next mi overwrites z2
  }
  if (t < 128) {
    const size_t obase = (size_t)NB*3*MC + ((size_t)b*COUTF + t)*MC + m0;
    if (BF) {
      uint4 v;
      v.x = (u32)f2b(outv[0]) | ((u32)f2b(outv[1]) << 16);
      v.y = (u32)f2b(outv[2]) | ((u32)f2b(outv[3]) << 16);
      v.z = (u32)f2b(outv[4]) | ((u32)f2b(outv[5]) << 16);
      v.w = (u32)f2b(outv[6]) | ((u32)f2b(outv[7]) << 16);
      *(uint4*)((u16*)out + obase) = v;
    } else {
      float* op = (float*)out + obase;
      *(float4*)(op)     = make_float4(outv[0],outv[1],outv[2],outv[3]);
      *(float4*)(op + 4) = make_float4(outv[4],outv[5],outv[6],outv[7]);
    }
  }
}

// ================================================================ FALLBACK PATH (round-4 fused)
template<int STAGE, bool BF>
__global__ __launch_bounds__(256) void mlp_kernel(
    const void* pts, const void* feats, const float* __restrict__ ftp, int ft,
    const void* w1p, const void* b1p, const void* w2p, const void* b2p,
    const void* w3p, const void* b3p,
    const float* __restrict__ centw, const int* __restrict__ gidxp,
    double* __restrict__ dstats, const float* __restrict__ fstats, void* out,
    const int* __restrict__ flagp)
{
  if ((*flagp != 0) != BF) return;

  constexpr int ACTF = 4352 + (STAGE>=2 ? 4352 : 0);
  constexpr int W1B  = BF ? 4352*2 : 4352*4;
  constexpr int W2B  = (STAGE>=2) ? (BF ? 4096*2 : 4096*4) : 0;
  constexpr int W3B  = (STAGE==3) ? (BF ? 8192*2 : 8192*4) : 0;
  constexpr int REDB = (STAGE==1) ? 8704 : 0;
  constexpr int SMB  = ACTF*4 + W1B + W2B + W3B + REDB;
  __shared__ alignas(16) unsigned char smem[SMB];
  __shared__ int gids[64];
  __shared__ float c3s[3];

  float* Xs  = (float*)smem;
  float* z1s = Xs + 4352;
  void*  w1t = smem + ACTF*4;
  void*  w2t = smem + ACTF*4 + W1B;
  void*  w3t = smem + ACTF*4 + W1B + W2B;
  float* red = (STAGE==1) ? (float*)(smem + ACTF*4 + W1B) : z1s;

  constexpr int TG = 8;
  const int t = threadIdx.x, lane = t & 63, wv = t >> 6;
  const int kq = lane >> 4, coq = lane & 15;
  const int co0 = coq * 4;
  const int co08 = coq * 8;
  const int k0  = wv*16 + kq*4;
  const int b   = blockIdx.x >> 7;
  const int m0  = (blockIdx.x & 127) * TG;

  for (int e = t; e < 4352; e += 256) {
    int cp = e >> 6, co = e & 63;
    int src = (cp < 64) ? (co*67 + cp + 3) : (cp < 67 ? co*67 + cp - 64 : -1);
    if constexpr (BF) ((u16*)w1t)[e]  = (src >= 0) ? ((const u16*)w1p)[src]  : (u16)0;
    else              ((float*)w1t)[e] = (src >= 0) ? ((const float*)w1p)[src] : 0.f;
  }
  if constexpr (STAGE >= 2)
    for (int e = t; e < 4096; e += 256) {
      int src = (e & 63)*64 + (e >> 6);
      if constexpr (BF) ((u16*)w2t)[e] = ((const u16*)w2p)[src];
      else              ((float*)w2t)[e] = ((const float*)w2p)[src];
    }
  if constexpr (STAGE == 3)
    for (int e = t; e < 8192; e += 256) {
      int src = (e & 127)*64 + (e >> 7);
      if constexpr (BF) ((u16*)w3t)[e] = ((const u16*)w3p)[src];
      else              ((float*)w3t)[e] = ((const float*)w3p)[src];
    }

  float b1v[4], b2v[4], sc1v[4], sh1v[4], sc2v[4], sh2v[4], b3v[8];
  #pragma unroll
  for (int j=0;j<4;++j) b1v[j] = io<BF>::ld(b1p, co0+j);
  if constexpr (STAGE >= 2) {
    #pragma unroll
    for (int j=0;j<4;++j) {
      b2v[j]  = io<BF>::ld(b2p, co0+j);
      sc1v[j] = fstats[co0+j]; sh1v[j] = fstats[64+co0+j];
    }
  }
  if constexpr (STAGE == 3) {
    #pragma unroll
    for (int j=0;j<4;++j) { sc2v[j] = fstats[128+co0+j]; sh2v[j] = fstats[192+co0+j]; }
    #pragma unroll
    for (int j=0;j<8;++j) b3v[j] = io<BF>::ld(b3p, co08+j);
  }
  float run_s = 0.f, run_q = 0.f;
  float outv[8];
  __syncthreads();

  for (int mi = 0; mi < TG; ++mi) {
    const int m = m0 + mi;
    const size_t g = (size_t)b*MC + m;
    if (t < 64) gids[t] = gidxp[g*KG + t];
    if (t < 3)  c3s[t]  = centw[g*3 + t];
    __syncthreads();
    {
      const int gi = gids[lane];
      float* xrow = Xs + lane*68;
      if (ft) {
        const float* fp = ftp + ((size_t)b*NPT + gi)*CINF + wv*16;
        float4 v0 = ((const float4*)fp)[0], v1 = ((const float4*)fp)[1];
        float4 v2 = ((const float4*)fp)[2], v3 = ((const float4*)fp)[3];
        float4* d = (float4*)(xrow + wv*16);
        d[0]=v0; d[1]=v1; d[2]=v2; d[3]=v3;
      } else {
        const int cs = wv*16;
        for (int c = cs; c < cs+16; ++c)
          xrow[c] = io<BF>::ld(feats, ((size_t)b*CINF + c)*NPT + gi);
      }
      if (wv == 0) {
        const size_t pbase = (size_t)b*3*NPT;
        xrow[64] = __fsub_rn(io<BF>::ld(pts, pbase + gi),         c3s[0]);
        xrow[65] = __fsub_rn(io<BF>::ld(pts, pbase + NPT + gi),   c3s[1]);
        xrow[66] = __fsub_rn(io<BF>::ld(pts, pbase + 2*NPT + gi), c3s[2]);
        xrow[67] = 0.f;
      }
    }
    __syncthreads();
    float acc[4][4];
    #pragma unroll
    for (int r=0;r<4;++r){
      #pragma unroll
      for (int j=0;j<4;++j) acc[r][j] = b1v[j];
    }
    {
      const float* xb = Xs + (size_t)k0*68;
      for (int c4 = 0; c4 < 17; ++c4) {
        float4 xv[4], wr[4];
        #pragma unroll
        for (int r=0;r<4;++r) xv[r] = *(const float4*)(xb + r*68 + c4*4);
        #pragma unroll
        for (int q=0;q<4;++q) wr[q] = ldw4<BF>(w1t, (c4*4+q)*64 + co0);
        #pragma unroll
        for (int q=0;q<4;++q){
          const float* w = (const float*)&wr[q];
          #pragma unroll
          for (int r=0;r<4;++r){
            const float x = ((const float*)&xv[r])[q];
            #pragma unroll
            for (int j=0;j<4;++j) acc[r][j] = fmaf(x, w[j], acc[r][j]);
          }
        }
      }
    }
    if constexpr (STAGE == 1) {
      #pragma unroll
      for (int j=0;j<4;++j){
        float s  = (acc[0][j]+acc[1][j]) + (acc[2][j]+acc[3][j]);
        float q2 = fmaf(acc[0][j],acc[0][j], fmaf(acc[1][j],acc[1][j],
                   fmaf(acc[2][j],acc[2][j], acc[3][j]*acc[3][j])));
        red[(co0+j)*17 + wv*4 + kq] = s;
        red[1088 + (co0+j)*17 + wv*4 + kq] = q2;
      }
      __syncthreads();
      if (t < 64) {
        const float* r1 = red + t*17; const float* r2 = red + 1088 + t*17;
        float s=0.f, q=0.f;
        #pragma unroll
        for (int i=0;i<16;++i){ s += r1[i]; q += r2[i]; }
        run_s += s; run_q += q;
      }
    } else {
      #pragma unroll
      for (int r=0;r<4;++r){
        float4 zv;
        zv.x = fmaxf(0.f, fmaf(acc[r][0], sc1v[0], sh1v[0]));
        zv.y = fmaxf(0.f, fmaf(acc[r][1], sc1v[1], sh1v[1]));
        zv.z = fmaxf(0.f, fmaf(acc[r][2], sc1v[2], sh1v[2]));
        zv.w = fmaxf(0.f, fmaf(acc[r][3], sc1v[3], sh1v[3]));
        *(float4*)(z1s + (size_t)(k0+r)*68 + co0) = zv;
      }
      __syncthreads();
      float acc2[4][4];
      #pragma unroll
      for (int r=0;r<4;++r){
        #pragma unroll
        for (int j=0;j<4;++j) acc2[r][j] = b2v[j];
      }
      {
        const float* zb = z1s + (size_t)k0*68;
        for (int c4 = 0; c4 < 16; ++c4) {
          float4 xv[4], wr[4];
          #pragma unroll
          for (int r=0;r<4;++r) xv[r] = *(const float4*)(zb + r*68 + c4*4);
          #pragma unroll
          for (int q=0;q<4;++q) wr[q] = ldw4<BF>(w2t, (c4*4+q)*64 + co0);
          #pragma unroll
          for (int q=0;q<4;++q){
            const float* w = (const float*)&wr[q];
            #pragma unroll
            for (int r=0;r<4;++r){
              const float x = ((const float*)&xv[r])[q];
              #pragma unroll
              for (int j=0;j<4;++j) acc2[r][j] = fmaf(x, w[j], acc2[r][j]);
            }
          }
        }
      }
      if constexpr (STAGE == 2) {
        __syncthreads();
        #pragma unroll
        for (int j=0;j<4;++j){
          float s  = (acc2[0][j]+acc2[1][j]) + (acc2[2][j]+acc2[3][j]);
          float q2 = fmaf(acc2[0][j],acc2[0][j], fmaf(acc2[1][j],acc2[1][j],
                     fmaf(acc2[2][j],acc2[2][j], acc2[3][j]*acc2[3][j])));
          red[(co0+j)*17 + wv*4 + kq] = s;
          red[1088 + (co0+j)*17 + wv*4 + kq] = q2;
        }
        __syncthreads();
        if (t < 64) {
          const float* r1 = red + t*17; const float* r2 = red + 1088 + t*17;
          float s=0.f, q=0.f;
          #pragma unroll
          for (int i=0;i<16;++i){ s += r1[i]; q += r2[i]; }
          run_s += s; run_q += q;
        }
      } else {
        #pragma unroll
        for (int r=0;r<4;++r){
          float4 zv;
          zv.x = fmaxf(0.f, fmaf(acc2[r][0], sc2v[0], sh2v[0]));
          zv.y = fmaxf(0.f, fmaf(acc2[r][1], sc2v[1], sh2v[1]));
          zv.z = fmaxf(0.f, fmaf(acc2[r][2], sc2v[2], sh2v[2]));
          zv.w = fmaxf(0.f, fmaf(acc2[r][3], sc2v[3], sh2v[3]));
          *(float4*)(Xs + (size_t)(k0+r)*68 + co0) = zv;
        }
        __syncthreads();
        float a3[4][8];
        #pragma unroll
        for (int r=0;r<4;++r){
          #pragma unroll
          for (int j=0;j<8;++j) a3[r][j] = b3v[j];
        }
        {
          const float* zb = Xs + (size_t)k0*68;
          for (int c4 = 0; c4 < 16; ++c4) {
            float4 xv[4], wr[4][2];
            #pragma unroll
            for (int r=0;r<4;++r) xv[r] = *(const float4*)(zb + r*68 + c4*4);
            #pragma unroll
            for (int q=0;q<4;++q) ldw8<BF>(w3t, (c4*4+q)*128 + co08, wr[q][0], wr[q][1]);
            #pragma unroll
            for (int q=0;q<4;++q){
              const float* w = (const float*)&wr[q][0];
              #pragma unroll
              for (int r=0;r<4;++r){
                const float x = ((const float*)&xv[r])[q];
                #pragma unroll
                for (int j=0;j<8;++j) a3[r][j] = fmaf(x, w[j], a3[r][j]);
              }
            }
          }
        }
        float* redm = red;
        #pragma unroll
        for (int j=0;j<8;++j){
          float mv = fmaxf(fmaxf(a3[0][j],a3[1][j]), fmaxf(a3[2][j],a3[3][j]));
          redm[(co08+j)*17 + wv*4 + kq] = mv;
        }
        __syncthreads();
        if (t < 128) {
          const float* rr = redm + t*17;
          float s = rr[0];
          #pragma unroll
          for (int i=1;i<16;++i) s = fmaxf(s, rr[i]);
          outv[mi] = s;
        }
      }
    }
  }
  if constexpr (STAGE <= 2) {
    if (t < 64) {
      atomicAdd(&dstats[(STAGE==1 ? 0 : 128) + lane], (double)run_s);
      atomicAdd(&dstats[(STAGE==1 ? 64 : 192) + lane], (double)run_q);
    }
  } else {
    if (t < 128) {
      const size_t obase = (size_t)NB*3*MC + ((size_t)b*COUTF + t)*MC + m0;
      if (BF) {
        uint4 v;
        v.x = (u32)f2b(outv[0]) | ((u32)f2b(outv[1]) << 16);
        v.y = (u32)f2b(outv[2]) | ((u32)f2b(outv[3]) << 16);
        v.z = (u32)f2b(outv[4]) | ((u32)f2b(outv[5]) << 16);
        v.w = (u32)f2b(outv[6]) | ((u32)f2b(outv[7]) << 16);
        *(uint4*)((u16*)out + obase) = v;
      } else {
        float* op = (float*)out + obase;
        *(float4*)(op)     = make_float4(outv[0],outv[1],outv[2],outv[3]);
        *(float4*)(op + 4) = make_float4(outv[4],outv[5],outv[6],outv[7]);
      }
    }
  }
}

// ---------------------------------------------------------------- BN finalize
__global__ void finalize_kernel(const double* __restrict__ dstats, float* __restrict__ fstats,
                                const void* g, const void* beta, const int* flagp, int stage)
{
  const int t = threadIdx.x;   // 64
  const int off = (stage==1) ? 0 : 128;
  const double inv = 1.0 / (double)PTOT;
  double mu = dstats[off + t] * inv;
  double q  = dstats[off + 64 + t] * inv;
  double var = q - mu*mu;
  if (var < 0.0) var = 0.0;
  float gg, bb;
  if (*flagp) { gg = blv(((const u16*)g)[t]);  bb = blv(((const u16*)beta)[t]); }
  else        { gg = ((const float*)g)[t];     bb = ((const float*)beta)[t]; }
  double scale = (double)gg / sqrt(var + 1e-5);
  fstats[off + t]      = (float)scale;
  fstats[off + 64 + t] = bb - (float)(mu*scale);
}

// ---------------------------------------------------------------- host
extern "C" void kernel_launch(void* const* d_in, const int* in_sizes, int n_in,
                              void* d_out, int out_size, void* d_ws, size_t ws_size,
                              hipStream_t stream)
{
  (void)in_sizes; (void)n_in; (void)out_size;
  const void* pts  = d_in[0];
  const void* feats= d_in[1];
  const void* w1   = d_in[2];
  const void* b1   = d_in[3];
  const void* g1   = d_in[4];
  const void* be1  = d_in[5];
  const void* w2   = d_in[6];
  const void* b2   = d_in[7];
  const void* g2   = d_in[8];
  const void* be2  = d_in[9];
  const void* w3   = d_in[10];
  const void* b3   = d_in[11];

  char* ws = (char*)d_ws;
  int*    flag   = (int*)ws;
  double* dstats = (double*)(ws + 64);
  float*  fstats = (float*)(ws + 2112);
  float*  centw  = (float*)(ws + 4096);
  int*    gidx   = (int*)(ws + 200704);
  float*  ftp    = (float*)(ws + 4395008);
  float*  A      = (float*)(ws + 21172224);
  const bool ft    = ws_size >= 21172224ull;
  const bool split = ws_size >= (21172224ull + 268435456ull);

  detect_kernel<<<1, 256, 0, stream>>>(pts, flag, dstats);
  fps_tr_kernel<<<ft ? (NB + NB*NPT/1024) : NB, 1024, 0, stream>>>(pts, feats, centw, ftp, d_out, flag);
  ballq_kernel<<<NB*MC/4, 256, 0, stream>>>(pts, centw, gidx, flag);

  const int GRID = NB*MC/8;
  if (split) {
    s1_kernel<true ><<<GRID, 256, 0, stream>>>(pts, ftp, w1, b1, centw, gidx, dstats, A, flag);
    s1_kernel<false><<<GRID, 256, 0, stream>>>(pts, ftp, w1, b1, centw, gidx, dstats, A, flag);
    finalize_kernel<<<1, 64, 0, stream>>>(dstats, fstats, g1, be1, flag, 1);
    s2_kernel<true ><<<GRID, 256, 0, stream>>>(w2, b2, fstats, dstats, A, flag);
    s2_kernel<false><<<GRID, 256, 0, stream>>>(w2, b2, fstats, dstats, A, flag);
    finalize_kernel<<<1, 64, 0, stream>>>(dstats, fstats, g2, be2, flag, 2);
    s3_kernel<true ><<<GRID, 256, 0, stream>>>(w3, b3, fstats, A, d_out, flag);
    s3_kernel<false><<<GRID, 256, 0, stream>>>(w3, b3, fstats, A, d_out, flag);
  } else {
    const int fti = ft ? 1 : 0;
    mlp_kernel<1,true ><<<GRID, 256, 0, stream>>>(pts,feats,ftp,fti,w1,b1,w2,b2,w3,b3,centw,gidx,dstats,fstats,d_out,flag);
    mlp_kernel<1,false><<<GRID, 256, 0, stream>>>(pts,feats,ftp,fti,w1,b1,w2,b2,w3,b3,centw,gidx,dstats,fstats,d_out,flag);
    finalize_kernel<<<1, 64, 0, stream>>>(dstats, fstats, g1, be1, flag, 1);
    mlp_kernel<2,true ><<<GRID, 256, 0, stream>>>(pts,feats,ftp,fti,w1,b1,w2,b2,w3,b3,centw,gidx,dstats,fstats,d_out,flag);
    mlp_kernel<2,false><<<GRID, 256, 0, stream>>>(pts,feats,ftp,fti,w1,b1,w2,b2,w3,b3,centw,gidx,dstats,fstats,d_out,flag);
    finalize_kernel<<<1, 64, 0, stream>>>(dstats, fstats, g2, be2, flag, 2);
    mlp_kernel<3,true ><<<GRID, 256, 0, stream>>>(pts,feats,ftp,fti,w1,b1,w2,b2,w3,b3,centw,gidx,dstats,fstats,d_out,flag);
    mlp_kernel<3,false><<<GRID, 256, 0, stream>>>(pts,feats,ftp,fti,w1,b1,w2,b2,w3,b3,centw,gidx,dstats,fstats,d_out,flag);
  }
}

// Round 6
// 1988.058 us; speedup vs baseline: 1.2544x; 1.2544x over previous
//
#include <hip/hip_runtime.h>

#define NB   16
#define NPT  4096
#define CINF 64
#define COUTF 128
#define MC   1024
#define KG   64
#define PTOT (NB*KG*MC)   /* 1048576 */

typedef unsigned short u16;
typedef unsigned int   u32;
typedef unsigned long long u64;

static __device__ __forceinline__ float blv(u16 v){ return __uint_as_float(((u32)v) << 16); }
static __device__ __forceinline__ u16 f2b(float f){
  u32 x = __float_as_uint(f);
  return (u16)((x + 0x7fffu + ((x >> 16) & 1u)) >> 16);
}

template<bool BF> struct io;
template<> struct io<true>{
  static __device__ __forceinline__ float ld(const void* p, size_t i){ return blv(((const u16*)p)[i]); }
  static __device__ __forceinline__ void st(void* p, size_t i, float v){ ((u16*)p)[i] = f2b(v); }
};
template<> struct io<false>{
  static __device__ __forceinline__ float ld(const void* p, size_t i){ return ((const float*)p)[i]; }
  static __device__ __forceinline__ void st(void* p, size_t i, float v){ ((float*)p)[i] = v; }
};

template<bool BF>
static __device__ __forceinline__ float4 ldw4(const void* w, int idx){
  if constexpr (BF) {
    ushort4 u = *(const ushort4*)((const u16*)w + idx);
    return make_float4(blv(u.x), blv(u.y), blv(u.z), blv(u.w));
  } else return *(const float4*)((const float*)w + idx);
}
template<bool BF>
static __device__ __forceinline__ void ldw8(const void* w, int idx, float4& a, float4& b){
  if constexpr (BF) {
    ushort4 u0 = *(const ushort4*)((const u16*)w + idx);
    ushort4 u1 = *(const ushort4*)((const u16*)w + idx + 4);
    a = make_float4(blv(u0.x), blv(u0.y), blv(u0.z), blv(u0.w));
    b = make_float4(blv(u1.x), blv(u1.y), blv(u1.z), blv(u1.w));
  } else {
    a = *(const float4*)((const float*)w + idx);
    b = *(const float4*)((const float*)w + idx + 4);
  }
}

// ---------------------------------------------------------------- detector + stats zero
__global__ __launch_bounds__(256) void detect_kernel(const void* pts, int* flagp, double* dstats)
{
  const int t = threadIdx.x;
  if (t < 64) {
    u32 w = ((const u32*)pts)[t];
    u64 m = __ballot((w & 0xFFFFu) < 0x4000u);
    if (t == 0) *flagp = (m == ~0ull) ? 1 : 0;
  }
  dstats[t] = 0.0;
}

// ---------------------------------------------------------------- FPS (256 thr) + fused transpose
template<bool BF>
static __device__ void fps_body(const void* pts, float* __restrict__ centw, void* out,
                                float* lx, float* ly, float* lz, u64 (*red)[4])
{
  const int t = threadIdx.x, b = blockIdx.x;
  const size_t pbase = (size_t)b*3*NPT;
  for (int i = t; i < NPT; i += 256) {
    lx[i] = io<BF>::ld(pts, pbase + i);
    ly[i] = io<BF>::ld(pts, pbase + NPT + i);
    lz[i] = io<BF>::ld(pts, pbase + 2*NPT + i);
  }
  __syncthreads();
  float qx[16],qy[16],qz[16],dd[16];
  const int base = t*16;
  #pragma unroll
  for (int j=0;j<16;++j){ qx[j]=lx[base+j]; qy[j]=ly[base+j]; qz[j]=lz[base+j]; dd[j]=1e10f; }
  int last = 0;
  const int lane = t & 63, wv = t >> 6;
  for (int it = 0; it < MC; ++it) {
    float cx = lx[last], cy = ly[last], cz = lz[last];
    if (t < 3) {
      float v = (t==0)?cx:((t==1)?cy:cz);
      centw[((size_t)b*MC + it)*3 + t] = v;
      io<BF>::st(out, (size_t)b*3*MC + (size_t)it*3 + t, v);
    }
    float bv = -1.f; int bi = base;
    #pragma unroll
    for (int j=0;j<16;++j) {
      float dx = __fsub_rn(qx[j], cx);
      float dy = __fsub_rn(qy[j], cy);
      float dz = __fsub_rn(qz[j], cz);
      float d  = __fadd_rn(__fadd_rn(__fmul_rn(dx,dx), __fmul_rn(dy,dy)), __fmul_rn(dz,dz));
      float nd = fminf(dd[j], d);
      dd[j] = nd;
      if (nd > bv) { bv = nd; bi = base + j; }   // strict >, ascending j => first max
    }
    // wave argmax: f32 max-reduce, then first lane holding the max (lanes ascend in index)
    float mv = bv;
    #pragma unroll
    for (int off = 1; off < 64; off <<= 1) mv = fmaxf(mv, __shfl_xor(mv, off, 64));
    u64 wm = __ballot(bv == mv);
    int fl = __ffsll((long long)wm) - 1;
    int wbi = __shfl(bi, fl, 64);
    if (lane == 0) red[it & 1][wv] = ((u64)__float_as_uint(mv) << 32) | (u32)(~wbi);
    __syncthreads();
    u64 k0 = red[it&1][0], k1 = red[it&1][1];
    u64 k2 = red[it&1][2], k3 = red[it&1][3];
    if (k1 > k0) k0 = k1;
    if (k3 > k2) k2 = k3;
    if (k2 > k0) k0 = k2;
    last = (int)(~(u32)k0);
  }
}

template<bool BF>
static __device__ void transpose_body(const void* feats, float* __restrict__ ftp)
{
  const int idx = (blockIdx.x - NB)*256 + threadIdx.x;   // B*N total
  const int b = idx >> 12, n = idx & (NPT-1);
  const size_t base = (size_t)b*CINF*NPT + n;
  float* o = ftp + (size_t)idx*CINF;
  #pragma unroll
  for (int c = 0; c < CINF; c += 4) {
    float4 v;
    v.x = io<BF>::ld(feats, base + (size_t)(c+0)*NPT);
    v.y = io<BF>::ld(feats, base + (size_t)(c+1)*NPT);
    v.z = io<BF>::ld(feats, base + (size_t)(c+2)*NPT);
    v.w = io<BF>::ld(feats, base + (size_t)(c+3)*NPT);
    *(float4*)(o + c) = v;
  }
}

__global__ __launch_bounds__(256) void fps_tr_kernel(const void* pts, const void* feats,
    float* centw, float* ftp, void* out, const int* flagp)
{
  __shared__ float lx[NPT], ly[NPT], lz[NPT];
  __shared__ u64 red[2][4];
  if (blockIdx.x < NB) {
    if (*flagp) fps_body<true >(pts, centw, out, lx, ly, lz, red);
    else        fps_body<false>(pts, centw, out, lx, ly, lz, red);
  } else {
    if (*flagp) transpose_body<true >(feats, ftp);
    else        transpose_body<false>(feats, ftp);
  }
}

// ---------------------------------------------------------------- ball query
template<bool BF>
static __device__ void ballq_body(const void* pts, const float* __restrict__ centw,
                                  int* __restrict__ gidx)
{
  const int lane = threadIdx.x & 63;
  const int g = blockIdx.x*4 + (threadIdx.x >> 6);
  const int b = g >> 10;
  const size_t pbase = (size_t)b*3*NPT;
  const float cx = centw[(size_t)g*3+0], cy = centw[(size_t)g*3+1], cz = centw[(size_t)g*3+2];
  int* gout = gidx + (size_t)g*KG;
  int taken = 0, idx0 = 0;
  for (int s = 0; s < NPT; s += 64) {
    int n = s + lane;
    float dx = __fsub_rn(cx, io<BF>::ld(pts, pbase + n));
    float dy = __fsub_rn(cy, io<BF>::ld(pts, pbase + NPT + n));
    float dz = __fsub_rn(cz, io<BF>::ld(pts, pbase + 2*NPT + n));
    float d2 = __fadd_rn(__fadd_rn(__fmul_rn(dx,dx), __fmul_rn(dy,dy)), __fmul_rn(dz,dz));
    u64 mask = __ballot(d2 <= 0.04f);
    if (mask) {
      if (taken == 0) idx0 = s + __ffsll((long long)mask) - 1;
      bool win = (mask >> lane) & 1;
      int pos = taken + __popcll(mask & ((1ull << lane) - 1ull));
      if (win && pos < KG) gout[pos] = n;
      taken += (int)__popcll(mask);
      if (taken >= KG) break;
    }
  }
  int cnt = taken < KG ? taken : KG;
  if (lane >= cnt) gout[lane] = idx0;
}

__global__ __launch_bounds__(256) void ballq_kernel(const void* pts, const float* centw,
                                                    int* gidx, const int* flagp)
{
  if (*flagp) ballq_body<true >(pts, centw, gidx);
  else        ballq_body<false>(pts, centw, gidx);
}

// ================================================================ LAYER-SPLIT PATH
// A[b,m,k,c] f32 tile in global ws. S1: gather+conv1->A+stats1. S2: bn1,relu,conv2 (in place)+stats2.
// S3: bn2,relu,conv3,max->out. S1/S2 process 2 groups per iteration (weight-load sharing),
// BN stats accumulate in registers (one block-end LDS reduction).

// ---------------- S1
template<bool BF>
__global__ __launch_bounds__(256) void s1_kernel(
    const void* pts, const float* __restrict__ ftp,
    const void* w1p, const void* b1p,
    const float* __restrict__ centw, const int* __restrict__ gidxp,
    double* __restrict__ dstats, float* __restrict__ A, const int* __restrict__ flagp)
{
  if ((*flagp != 0) != BF) return;
  __shared__ alignas(16) float Xs[2][4352];                    // [g][64][68]
  __shared__ alignas(16) unsigned char w1raw[BF ? 4352*2 : 4352*4];
  __shared__ int gids[128];
  __shared__ float c3s[6];

  const int t = threadIdx.x, lane = t & 63, wv = t >> 6;
  const int kq = lane >> 4, coq = lane & 15;
  const int co0 = coq * 4;
  const int k0  = wv*16 + kq*4;
  const int b   = blockIdx.x >> 7;
  const int m0  = (blockIdx.x & 127) * 8;

  for (int e = t; e < 4352; e += 256) {
    int cp = e >> 6, co = e & 63;
    int src = (cp < 64) ? (co*67 + cp + 3) : (cp < 67 ? co*67 + cp - 64 : -1);
    if constexpr (BF) ((u16*)w1raw)[e]   = (src >= 0) ? ((const u16*)w1p)[src]   : (u16)0;
    else              ((float*)w1raw)[e] = (src >= 0) ? ((const float*)w1p)[src] : 0.f;
  }
  float b1v[4];
  #pragma unroll
  for (int j=0;j<4;++j) b1v[j] = io<BF>::ld(b1p, co0+j);
  float sp[4] = {0,0,0,0}, qp[4] = {0,0,0,0};
  __syncthreads();

  for (int mo = 0; mo < 4; ++mo) {
    const size_t g0 = (size_t)b*MC + m0 + mo*2;
    if (t < 128) gids[t] = gidxp[g0*KG + t];
    if (t < 6)   c3s[t]  = centw[g0*3 + t];
    __syncthreads();
    #pragma unroll
    for (int g = 0; g < 2; ++g) {
      const int gi = gids[g*64 + lane];
      float* xrow = Xs[g] + lane*68;
      const float* fp = ftp + ((size_t)b*NPT + gi)*CINF + wv*16;
      float4 v0 = ((const float4*)fp)[0], v1 = ((const float4*)fp)[1];
      float4 v2 = ((const float4*)fp)[2], v3 = ((const float4*)fp)[3];
      float4* d = (float4*)(xrow + wv*16);
      d[0]=v0; d[1]=v1; d[2]=v2; d[3]=v3;
      if (wv == 0) {
        const size_t pbase = (size_t)b*3*NPT;
        xrow[64] = __fsub_rn(io<BF>::ld(pts, pbase + gi),         c3s[g*3+0]);
        xrow[65] = __fsub_rn(io<BF>::ld(pts, pbase + NPT + gi),   c3s[g*3+1]);
        xrow[66] = __fsub_rn(io<BF>::ld(pts, pbase + 2*NPT + gi), c3s[g*3+2]);
        xrow[67] = 0.f;
      }
    }
    __syncthreads();
    float acc[2][4][4];
    #pragma unroll
    for (int g=0;g<2;++g)
      #pragma unroll
      for (int r=0;r<4;++r)
        #pragma unroll
        for (int j=0;j<4;++j) acc[g][r][j] = b1v[j];
    {
      const float* xb0 = Xs[0] + (size_t)k0*68;
      const float* xb1 = Xs[1] + (size_t)k0*68;
      for (int c4 = 0; c4 < 17; ++c4) {
        float4 wr[4];
        #pragma unroll
        for (int q=0;q<4;++q) wr[q] = ldw4<BF>(w1raw, (c4*4+q)*64 + co0);
        float4 xv[2][4];
        #pragma unroll
        for (int r=0;r<4;++r){ xv[0][r] = *(const float4*)(xb0 + r*68 + c4*4);
                               xv[1][r] = *(const float4*)(xb1 + r*68 + c4*4); }
        #pragma unroll
        for (int q=0;q<4;++q){
          const float* w = (const float*)&wr[q];
          #pragma unroll
          for (int g=0;g<2;++g)
            #pragma unroll
            for (int r=0;r<4;++r){
              const float x = ((const float*)&xv[g][r])[q];
              #pragma unroll
              for (int j=0;j<4;++j) acc[g][r][j] = fmaf(x, w[j], acc[g][r][j]);
            }
        }
      }
    }
    #pragma unroll
    for (int g=0;g<2;++g){
      float* Ag = A + (g0+g)*4096;
      #pragma unroll
      for (int r=0;r<4;++r)
        *(float4*)(Ag + (size_t)(k0+r)*64 + co0) = make_float4(acc[g][r][0],acc[g][r][1],acc[g][r][2],acc[g][r][3]);
      #pragma unroll
      for (int j=0;j<4;++j){
        sp[j] += (acc[g][0][j]+acc[g][1][j]) + (acc[g][2][j]+acc[g][3][j]);
        qp[j]  = fmaf(acc[g][0][j],acc[g][0][j], fmaf(acc[g][1][j],acc[g][1][j],
                 fmaf(acc[g][2][j],acc[g][2][j], fmaf(acc[g][3][j],acc[g][3][j], qp[j]))));
      }
    }
    __syncthreads();   // Xs/gids reads done before next iteration overwrites
  }
  // block-end stats reduction (reuse Xs)
  float* sbuf = Xs[0];
  #pragma unroll
  for (int j=0;j<4;++j){ sbuf[t*4+j] = sp[j]; sbuf[1024 + t*4+j] = qp[j]; }
  __syncthreads();
  if (t < 64) {
    const int cq = t >> 2, jj = t & 3;
    float s=0.f, q=0.f;
    #pragma unroll
    for (int i=0;i<16;++i){
      const int tp = cq + 16*i;
      s += sbuf[tp*4 + jj];
      q += sbuf[1024 + tp*4 + jj];
    }
    atomicAdd(&dstats[t],      (double)s);
    atomicAdd(&dstats[64 + t], (double)q);
  }
}

// ---------------- S2 (in-place A update)
template<bool BF>
__global__ __launch_bounds__(256) void s2_kernel(
    const void* w2p, const void* b2p,
    const float* __restrict__ fstats, double* __restrict__ dstats,
    float* __restrict__ A, const int* __restrict__ flagp)
{
  if ((*flagp != 0) != BF) return;
  __shared__ alignas(16) float z1[2][4352];
  __shared__ alignas(16) unsigned char w2raw[BF ? 4096*2 : 4096*4];
  __shared__ float scsh[128];

  const int t = threadIdx.x, lane = t & 63, wv = t >> 6;
  const int kq = lane >> 4, coq = lane & 15;
  const int co0 = coq * 4;
  const int k0  = wv*16 + kq*4;
  const int b   = blockIdx.x >> 7;
  const int m0  = (blockIdx.x & 127) * 8;

  for (int e = t; e < 4096; e += 256) {
    int src = (e & 63)*64 + (e >> 6);
    if constexpr (BF) ((u16*)w2raw)[e] = ((const u16*)w2p)[src];
    else              ((float*)w2raw)[e] = ((const float*)w2p)[src];
  }
  if (t < 128) scsh[t] = fstats[t];
  float b2v[4];
  #pragma unroll
  for (int j=0;j<4;++j) b2v[j] = io<BF>::ld(b2p, co0+j);
  __syncthreads();
  const int c0 = (t*4) & 63;
  float scr[4], shr[4];
  #pragma unroll
  for (int j=0;j<4;++j){ scr[j] = scsh[c0+j]; shr[j] = scsh[64+c0+j]; }
  float sp[4] = {0,0,0,0}, qp[4] = {0,0,0,0};

  for (int mo = 0; mo < 4; ++mo) {
    const size_t g0 = (size_t)b*MC + m0 + mo*2;
    #pragma unroll
    for (int g=0;g<2;++g){
      float* Ag = A + (g0+g)*4096;
      #pragma unroll
      for (int u=0;u<4;++u){
        const int e = u*1024 + t*4;
        float4 v = *(const float4*)(Ag + e);
        const int row = e >> 6;
        float4 z;
        z.x = fmaxf(0.f, fmaf(v.x, scr[0], shr[0]));
        z.y = fmaxf(0.f, fmaf(v.y, scr[1], shr[1]));
        z.z = fmaxf(0.f, fmaf(v.z, scr[2], shr[2]));
        z.w = fmaxf(0.f, fmaf(v.w, scr[3], shr[3]));
        *(float4*)(z1[g] + (size_t)row*68 + c0) = z;
      }
    }
    __syncthreads();
    float acc[2][4][4];
    #pragma unroll
    for (int g=0;g<2;++g)
      #pragma unroll
      for (int r=0;r<4;++r)
        #pragma unroll
        for (int j=0;j<4;++j) acc[g][r][j] = b2v[j];
    {
      const float* zb0 = z1[0] + (size_t)k0*68;
      const float* zb1 = z1[1] + (size_t)k0*68;
      for (int c4 = 0; c4 < 16; ++c4) {
        float4 wr[4];
        #pragma unroll
        for (int q=0;q<4;++q) wr[q] = ldw4<BF>(w2raw, (c4*4+q)*64 + co0);
        float4 xv[2][4];
        #pragma unroll
        for (int r=0;r<4;++r){ xv[0][r] = *(const float4*)(zb0 + r*68 + c4*4);
                               xv[1][r] = *(const float4*)(zb1 + r*68 + c4*4); }
        #pragma unroll
        for (int q=0;q<4;++q){
          const float* w = (const float*)&wr[q];
          #pragma unroll
          for (int g=0;g<2;++g)
            #pragma unroll
            for (int r=0;r<4;++r){
              const float x = ((const float*)&xv[g][r])[q];
              #pragma unroll
              for (int j=0;j<4;++j) acc[g][r][j] = fmaf(x, w[j], acc[g][r][j]);
            }
        }
      }
    }
    #pragma unroll
    for (int g=0;g<2;++g){
      float* Ag = A + (g0+g)*4096;
      #pragma unroll
      for (int r=0;r<4;++r)
        *(float4*)(Ag + (size_t)(k0+r)*64 + co0) = make_float4(acc[g][r][0],acc[g][r][1],acc[g][r][2],acc[g][r][3]);
      #pragma unroll
      for (int j=0;j<4;++j){
        sp[j] += (acc[g][0][j]+acc[g][1][j]) + (acc[g][2][j]+acc[g][3][j]);
        qp[j]  = fmaf(acc[g][0][j],acc[g][0][j], fmaf(acc[g][1][j],acc[g][1][j],
                 fmaf(acc[g][2][j],acc[g][2][j], fmaf(acc[g][3][j],acc[g][3][j], qp[j]))));
      }
    }
    __syncthreads();   // z1 reads done before next stage-in
  }
  float* sbuf = z1[0];
  #pragma unroll
  for (int j=0;j<4;++j){ sbuf[t*4+j] = sp[j]; sbuf[1024 + t*4+j] = qp[j]; }
  __syncthreads();
  if (t < 64) {
    const int cq = t >> 2, jj = t & 3;
    float s=0.f, q=0.f;
    #pragma unroll
    for (int i=0;i<16;++i){
      const int tp = cq + 16*i;
      s += sbuf[tp*4 + jj];
      q += sbuf[1024 + tp*4 + jj];
    }
    atomicAdd(&dstats[128 + t], (double)s);
    atomicAdd(&dstats[192 + t], (double)q);
  }
}

// ---------------- S3
template<bool BF>
__global__ __launch_bounds__(256) void s3_kernel(
    const void* w3p, const void* b3p,
    const float* __restrict__ fstats, const float* __restrict__ A,
    void* out, const int* __restrict__ flagp)
{
  if ((*flagp != 0) != BF) return;
  __shared__ alignas(16) float z2[4352];                   // redm overlays after conv3
  __shared__ alignas(16) unsigned char w3raw[BF ? 8192*2 : 8192*4];
  __shared__ float scsh[128];

  constexpr int TG = 8;
  const int t = threadIdx.x, lane = t & 63, wv = t >> 6;
  const int kq = lane >> 4, coq = lane & 15;
  const int co08 = coq * 8;
  const int k0  = wv*16 + kq*4;
  const int b   = blockIdx.x >> 7;
  const int m0  = (blockIdx.x & 127) * TG;

  for (int e = t; e < 8192; e += 256) {
    int src = (e & 127)*64 + (e >> 7);
    if constexpr (BF) ((u16*)w3raw)[e] = ((const u16*)w3p)[src];
    else              ((float*)w3raw)[e] = ((const float*)w3p)[src];
  }
  if (t < 128) scsh[t] = fstats[128 + t];
  float b3v[8];
  #pragma unroll
  for (int j=0;j<8;++j) b3v[j] = io<BF>::ld(b3p, co08+j);
  __syncthreads();
  const int c0 = (t*4) & 63;
  float scr[4], shr[4];
  #pragma unroll
  for (int j=0;j<4;++j){ scr[j] = scsh[c0+j]; shr[j] = scsh[64+c0+j]; }
  float outv[8];

  for (int mi = 0; mi < TG; ++mi) {
    const size_t g = (size_t)b*MC + (m0 + mi);
    const float* Ag = A + g*4096;
    #pragma unroll
    for (int u=0;u<4;++u){
      const int e = u*1024 + t*4;
      float4 v = *(const float4*)(Ag + e);
      const int row = e >> 6;
      float4 z;
      z.x = fmaxf(0.f, fmaf(v.x, scr[0], shr[0]));
      z.y = fmaxf(0.f, fmaf(v.y, scr[1], shr[1]));
      z.z = fmaxf(0.f, fmaf(v.z, scr[2], shr[2]));
      z.w = fmaxf(0.f, fmaf(v.w, scr[3], shr[3]));
      *(float4*)(z2 + (size_t)row*68 + c0) = z;
    }
    __syncthreads();
    float a3[4][8];
    #pragma unroll
    for (int r=0;r<4;++r){
      #pragma unroll
      for (int j=0;j<8;++j) a3[r][j] = b3v[j];
    }
    {
      const float* zb = z2 + (size_t)k0*68;
      for (int c4 = 0; c4 < 16; ++c4) {
        float4 xv[4], wr[4][2];
        #pragma unroll
        for (int r=0;r<4;++r) xv[r] = *(const float4*)(zb + r*68 + c4*4);
        #pragma unroll
        for (int q=0;q<4;++q) ldw8<BF>(w3raw, (c4*4+q)*128 + co08, wr[q][0], wr[q][1]);
        #pragma unroll
        for (int q=0;q<4;++q){
          const float* w = (const float*)&wr[q][0];
          #pragma unroll
          for (int r=0;r<4;++r){
            const float x = ((const float*)&xv[r])[q];
            #pragma unroll
            for (int j=0;j<8;++j) a3[r][j] = fmaf(x, w[j], a3[r][j]);
          }
        }
      }
    }
    __syncthreads();                 // all conv3 z2-reads done before redm overlays z2
    float* redm = z2;
    #pragma unroll
    for (int j=0;j<8;++j){
      float mv = fmaxf(fmaxf(a3[0][j],a3[1][j]), fmaxf(a3[2][j],a3[3][j]));
      redm[(co08+j)*17 + wv*4 + kq] = mv;
    }
    __syncthreads();
    if (t < 128) {
      const float* rr = redm + t*17;
      float s = rr[0];
      #pragma unroll
      for (int i=1;i<16;++i) s = fmaxf(s, rr[i]);
      outv[mi] = s;
    }
    __syncthreads();                 // redm reads done before next mi overwrites z2
  }
  if (t < 128) {
    const size_t obase = (size_t)NB*3*MC + ((size_t)b*COUTF + t)*MC + m0;
    if (BF) {
      uint4 v;
      v.x = (u32)f2b(outv[0]) | ((u32)f2b(outv[1]) << 16);
      v.y = (u32)f2b(outv[2]) | ((u32)f2b(outv[3]) << 16);
      v.z = (u32)f2b(outv[4]) | ((u32)f2b(outv[5]) << 16);
      v.w = (u32)f2b(outv[6]) | ((u32)f2b(outv[7]) << 16);
      *(uint4*)((u16*)out + obase) = v;
    } else {
      float* op = (float*)out + obase;
      *(float4*)(op)     = make_float4(outv[0],outv[1],outv[2],outv[3]);
      *(float4*)(op + 4) = make_float4(outv[4],outv[5],outv[6],outv[7]);
    }
  }
}

// ================================================================ FALLBACK PATH (fused)
template<int STAGE, bool BF>
__global__ __launch_bounds__(256) void mlp_kernel(
    const void* pts, const void* feats, const float* __restrict__ ftp, int ft,
    const void* w1p, const void* b1p, const void* w2p, const void* b2p,
    const void* w3p, const void* b3p,
    const float* __restrict__ centw, const int* __restrict__ gidxp,
    double* __restrict__ dstats, const float* __restrict__ fstats, void* out,
    const int* __restrict__ flagp)
{
  if ((*flagp != 0) != BF) return;

  constexpr int ACTF = 4352 + (STAGE>=2 ? 4352 : 0);
  constexpr int W1B  = BF ? 4352*2 : 4352*4;
  constexpr int W2B  = (STAGE>=2) ? (BF ? 4096*2 : 4096*4) : 0;
  constexpr int W3B  = (STAGE==3) ? (BF ? 8192*2 : 8192*4) : 0;
  constexpr int REDB = (STAGE==1) ? 8704 : 0;
  constexpr int SMB  = ACTF*4 + W1B + W2B + W3B + REDB;
  __shared__ alignas(16) unsigned char smem[SMB];
  __shared__ int gids[64];
  __shared__ float c3s[3];

  float* Xs  = (float*)smem;
  float* z1s = Xs + 4352;
  void*  w1t = smem + ACTF*4;
  void*  w2t = smem + ACTF*4 + W1B;
  void*  w3t = smem + ACTF*4 + W1B + W2B;
  float* red = (STAGE==1) ? (float*)(smem + ACTF*4 + W1B) : z1s;

  constexpr int TG = 8;
  const int t = threadIdx.x, lane = t & 63, wv = t >> 6;
  const int kq = lane >> 4, coq = lane & 15;
  const int co0 = coq * 4;
  const int co08 = coq * 8;
  const int k0  = wv*16 + kq*4;
  const int b   = blockIdx.x >> 7;
  const int m0  = (blockIdx.x & 127) * TG;

  for (int e = t; e < 4352; e += 256) {
    int cp = e >> 6, co = e & 63;
    int src = (cp < 64) ? (co*67 + cp + 3) : (cp < 67 ? co*67 + cp - 64 : -1);
    if constexpr (BF) ((u16*)w1t)[e]  = (src >= 0) ? ((const u16*)w1p)[src]  : (u16)0;
    else              ((float*)w1t)[e] = (src >= 0) ? ((const float*)w1p)[src] : 0.f;
  }
  if constexpr (STAGE >= 2)
    for (int e = t; e < 4096; e += 256) {
      int src = (e & 63)*64 + (e >> 6);
      if constexpr (BF) ((u16*)w2t)[e] = ((const u16*)w2p)[src];
      else              ((float*)w2t)[e] = ((const float*)w2p)[src];
    }
  if constexpr (STAGE == 3)
    for (int e = t; e < 8192; e += 256) {
      int src = (e & 127)*64 + (e >> 7);
      if constexpr (BF) ((u16*)w3t)[e] = ((const u16*)w3p)[src];
      else              ((float*)w3t)[e] = ((const float*)w3p)[src];
    }

  float b1v[4], b2v[4], sc1v[4], sh1v[4], sc2v[4], sh2v[4], b3v[8];
  #pragma unroll
  for (int j=0;j<4;++j) b1v[j] = io<BF>::ld(b1p, co0+j);
  if constexpr (STAGE >= 2) {
    #pragma unroll
    for (int j=0;j<4;++j) {
      b2v[j]  = io<BF>::ld(b2p, co0+j);
      sc1v[j] = fstats[co0+j]; sh1v[j] = fstats[64+co0+j];
    }
  }
  if constexpr (STAGE == 3) {
    #pragma unroll
    for (int j=0;j<4;++j) { sc2v[j] = fstats[128+co0+j]; sh2v[j] = fstats[192+co0+j]; }
    #pragma unroll
    for (int j=0;j<8;++j) b3v[j] = io<BF>::ld(b3p, co08+j);
  }
  float run_s = 0.f, run_q = 0.f;
  float outv[8];
  __syncthreads();

  for (int mi = 0; mi < TG; ++mi) {
    const int m = m0 + mi;
    const size_t g = (size_t)b*MC + m;
    if (t < 64) gids[t] = gidxp[g*KG + t];
    if (t < 3)  c3s[t]  = centw[g*3 + t];
    __syncthreads();
    {
      const int gi = gids[lane];
      float* xrow = Xs + lane*68;
      if (ft) {
        const float* fp = ftp + ((size_t)b*NPT + gi)*CINF + wv*16;
        float4 v0 = ((const float4*)fp)[0], v1 = ((const float4*)fp)[1];
        float4 v2 = ((const float4*)fp)[2], v3 = ((const float4*)fp)[3];
        float4* d = (float4*)(xrow + wv*16);
        d[0]=v0; d[1]=v1; d[2]=v2; d[3]=v3;
      } else {
        const int cs = wv*16;
        for (int c = cs; c < cs+16; ++c)
          xrow[c] = io<BF>::ld(feats, ((size_t)b*CINF + c)*NPT + gi);
      }
      if (wv == 0) {
        const size_t pbase = (size_t)b*3*NPT;
        xrow[64] = __fsub_rn(io<BF>::ld(pts, pbase + gi),         c3s[0]);
        xrow[65] = __fsub_rn(io<BF>::ld(pts, pbase + NPT + gi),   c3s[1]);
        xrow[66] = __fsub_rn(io<BF>::ld(pts, pbase + 2*NPT + gi), c3s[2]);
        xrow[67] = 0.f;
      }
    }
    __syncthreads();
    float acc[4][4];
    #pragma unroll
    for (int r=0;r<4;++r){
      #pragma unroll
      for (int j=0;j<4;++j) acc[r][j] = b1v[j];
    }
    {
      const float* xb = Xs + (size_t)k0*68;
      for (int c4 = 0; c4 < 17; ++c4) {
        float4 xv[4], wr[4];
        #pragma unroll
        for (int r=0;r<4;++r) xv[r] = *(const float4*)(xb + r*68 + c4*4);
        #pragma unroll
        for (int q=0;q<4;++q) wr[q] = ldw4<BF>(w1t, (c4*4+q)*64 + co0);
        #pragma unroll
        for (int q=0;q<4;++q){
          const float* w = (const float*)&wr[q];
          #pragma unroll
          for (int r=0;r<4;++r){
            const float x = ((const float*)&xv[r])[q];
            #pragma unroll
            for (int j=0;j<4;++j) acc[r][j] = fmaf(x, w[j], acc[r][j]);
          }
        }
      }
    }
    if constexpr (STAGE == 1) {
      #pragma unroll
      for (int j=0;j<4;++j){
        float s  = (acc[0][j]+acc[1][j]) + (acc[2][j]+acc[3][j]);
        float q2 = fmaf(acc[0][j],acc[0][j], fmaf(acc[1][j],acc[1][j],
                   fmaf(acc[2][j],acc[2][j], acc[3][j]*acc[3][j])));
        red[(co0+j)*17 + wv*4 + kq] = s;
        red[1088 + (co0+j)*17 + wv*4 + kq] = q2;
      }
      __syncthreads();
      if (t < 64) {
        const float* r1 = red + t*17; const float* r2 = red + 1088 + t*17;
        float s=0.f, q=0.f;
        #pragma unroll
        for (int i=0;i<16;++i){ s += r1[i]; q += r2[i]; }
        run_s += s; run_q += q;
      }
    } else {
      #pragma unroll
      for (int r=0;r<4;++r){
        float4 zv;
        zv.x = fmaxf(0.f, fmaf(acc[r][0], sc1v[0], sh1v[0]));
        zv.y = fmaxf(0.f, fmaf(acc[r][1], sc1v[1], sh1v[1]));
        zv.z = fmaxf(0.f, fmaf(acc[r][2], sc1v[2], sh1v[2]));
        zv.w = fmaxf(0.f, fmaf(acc[r][3], sc1v[3], sh1v[3]));
        *(float4*)(z1s + (size_t)(k0+r)*68 + co0) = zv;
      }
      __syncthreads();
      float acc2[4][4];
      #pragma unroll
      for (int r=0;r<4;++r){
        #pragma unroll
        for (int j=0;j<4;++j) acc2[r][j] = b2v[j];
      }
      {
        const float* zb = z1s + (size_t)k0*68;
        for (int c4 = 0; c4 < 16; ++c4) {
          float4 xv[4], wr[4];
          #pragma unroll
          for (int r=0;r<4;++r) xv[r] = *(const float4*)(zb + r*68 + c4*4);
          #pragma unroll
          for (int q=0;q<4;++q) wr[q] = ldw4<BF>(w2t, (c4*4+q)*64 + co0);
          #pragma unroll
          for (int q=0;q<4;++q){
            const float* w = (const float*)&wr[q];
            #pragma unroll
            for (int r=0;r<4;++r){
              const float x = ((const float*)&xv[r])[q];
              #pragma unroll
              for (int j=0;j<4;++j) acc2[r][j] = fmaf(x, w[j], acc2[r][j]);
            }
          }
        }
      }
      if constexpr (STAGE == 2) {
        __syncthreads();
        #pragma unroll
        for (int j=0;j<4;++j){
          float s  = (acc2[0][j]+acc2[1][j]) + (acc2[2][j]+acc2[3][j]);
          float q2 = fmaf(acc2[0][j],acc2[0][j], fmaf(acc2[1][j],acc2[1][j],
                     fmaf(acc2[2][j],acc2[2][j], acc2[3][j]*acc2[3][j])));
          red[(co0+j)*17 + wv*4 + kq] = s;
          red[1088 + (co0+j)*17 + wv*4 + kq] = q2;
        }
        __syncthreads();
        if (t < 64) {
          const float* r1 = red + t*17; const float* r2 = red + 1088 + t*17;
          float s=0.f, q=0.f;
          #pragma unroll
          for (int i=0;i<16;++i){ s += r1[i]; q += r2[i]; }
          run_s += s; run_q += q;
        }
      } else {
        #pragma unroll
        for (int r=0;r<4;++r){
          float4 zv;
          zv.x = fmaxf(0.f, fmaf(acc2[r][0], sc2v[0], sh2v[0]));
          zv.y = fmaxf(0.f, fmaf(acc2[r][1], sc2v[1], sh2v[1]));
          zv.z = fmaxf(0.f, fmaf(acc2[r][2], sc2v[2], sh2v[2]));
          zv.w = fmaxf(0.f, fmaf(acc2[r][3], sc2v[3], sh2v[3]));
          *(float4*)(Xs + (size_t)(k0+r)*68 + co0) = zv;
        }
        __syncthreads();
        float a3[4][8];
        #pragma unroll
        for (int r=0;r<4;++r){
          #pragma unroll
          for (int j=0;j<8;++j) a3[r][j] = b3v[j];
        }
        {
          const float* zb = Xs + (size_t)k0*68;
          for (int c4 = 0; c4 < 16; ++c4) {
            float4 xv[4], wr[4][2];
            #pragma unroll
            for (int r=0;r<4;++r) xv[r] = *(const float4*)(zb + r*68 + c4*4);
            #pragma unroll
            for (int q=0;q<4;++q) ldw8<BF>(w3t, (c4*4+q)*128 + co08, wr[q][0], wr[q][1]);
            #pragma unroll
            for (int q=0;q<4;++q){
              const float* w = (const float*)&wr[q][0];
              #pragma unroll
              for (int r=0;r<4;++r){
                const float x = ((const float*)&xv[r])[q];
                #pragma unroll
                for (int j=0;j<8;++j) a3[r][j] = fmaf(x, w[j], a3[r][j]);
              }
            }
          }
        }
        float* redm = red;
        #pragma unroll
        for (int j=0;j<8;++j){
          float mv = fmaxf(fmaxf(a3[0][j],a3[1][j]), fmaxf(a3[2][j],a3[3][j]));
          redm[(co08+j)*17 + wv*4 + kq] = mv;
        }
        __syncthreads();
        if (t < 128) {
          const float* rr = redm + t*17;
          float s = rr[0];
          #pragma unroll
          for (int i=1;i<16;++i) s = fmaxf(s, rr[i]);
          outv[mi] = s;
        }
      }
    }
  }
  if constexpr (STAGE <= 2) {
    if (t < 64) {
      atomicAdd(&dstats[(STAGE==1 ? 0 : 128) + lane], (double)run_s);
      atomicAdd(&dstats[(STAGE==1 ? 64 : 192) + lane], (double)run_q);
    }
  } else {
    if (t < 128) {
      const size_t obase = (size_t)NB*3*MC + ((size_t)b*COUTF + t)*MC + m0;
      if (BF) {
        uint4 v;
        v.x = (u32)f2b(outv[0]) | ((u32)f2b(outv[1]) << 16);
        v.y = (u32)f2b(outv[2]) | ((u32)f2b(outv[3]) << 16);
        v.z = (u32)f2b(outv[4]) | ((u32)f2b(outv[5]) << 16);
        v.w = (u32)f2b(outv[6]) | ((u32)f2b(outv[7]) << 16);
        *(uint4*)((u16*)out + obase) = v;
      } else {
        float* op = (float*)out + obase;
        *(float4*)(op)     = make_float4(outv[0],outv[1],outv[2],outv[3]);
        *(float4*)(op + 4) = make_float4(outv[4],outv[5],outv[6],outv[7]);
      }
    }
  }
}

// ---------------------------------------------------------------- BN finalize
__global__ void finalize_kernel(const double* __restrict__ dstats, float* __restrict__ fstats,
                                const void* g, const void* beta, const int* flagp, int stage)
{
  const int t = threadIdx.x;   // 64
  const int off = (stage==1) ? 0 : 128;
  const double inv = 1.0 / (double)PTOT;
  double mu = dstats[off + t] * inv;
  double q  = dstats[off + 64 + t] * inv;
  double var = q - mu*mu;
  if (var < 0.0) var = 0.0;
  float gg, bb;
  if (*flagp) { gg = blv(((const u16*)g)[t]);  bb = blv(((const u16*)beta)[t]); }
  else        { gg = ((const float*)g)[t];     bb = ((const float*)beta)[t]; }
  double scale = (double)gg / sqrt(var + 1e-5);
  fstats[off + t]      = (float)scale;
  fstats[off + 64 + t] = bb - (float)(mu*scale);
}

// ---------------------------------------------------------------- host
extern "C" void kernel_launch(void* const* d_in, const int* in_sizes, int n_in,
                              void* d_out, int out_size, void* d_ws, size_t ws_size,
                              hipStream_t stream)
{
  (void)in_sizes; (void)n_in; (void)out_size;
  const void* pts  = d_in[0];
  const void* feats= d_in[1];
  const void* w1   = d_in[2];
  const void* b1   = d_in[3];
  const void* g1   = d_in[4];
  const void* be1  = d_in[5];
  const void* w2   = d_in[6];
  const void* b2   = d_in[7];
  const void* g2   = d_in[8];
  const void* be2  = d_in[9];
  const void* w3   = d_in[10];
  const void* b3   = d_in[11];

  char* ws = (char*)d_ws;
  int*    flag   = (int*)ws;
  double* dstats = (double*)(ws + 64);
  float*  fstats = (float*)(ws + 2112);
  float*  centw  = (float*)(ws + 4096);
  int*    gidx   = (int*)(ws + 200704);
  float*  ftp    = (float*)(ws + 4395008);
  float*  A      = (float*)(ws + 21172224);
  const bool ft    = ws_size >= 21172224ull;
  const bool split = ws_size >= (21172224ull + 268435456ull);

  detect_kernel<<<1, 256, 0, stream>>>(pts, flag, dstats);
  fps_tr_kernel<<<ft ? (NB + NB*NPT/256) : NB, 256, 0, stream>>>(pts, feats, centw, ftp, d_out, flag);
  ballq_kernel<<<NB*MC/4, 256, 0, stream>>>(pts, centw, gidx, flag);

  const int GRID = NB*MC/8;
  if (split) {
    s1_kernel<true ><<<GRID, 256, 0, stream>>>(pts, ftp, w1, b1, centw, gidx, dstats, A, flag);
    s1_kernel<false><<<GRID, 256, 0, stream>>>(pts, ftp, w1, b1, centw, gidx, dstats, A, flag);
    finalize_kernel<<<1, 64, 0, stream>>>(dstats, fstats, g1, be1, flag, 1);
    s2_kernel<true ><<<GRID, 256, 0, stream>>>(w2, b2, fstats, dstats, A, flag);
    s2_kernel<false><<<GRID, 256, 0, stream>>>(w2, b2, fstats, dstats, A, flag);
    finalize_kernel<<<1, 64, 0, stream>>>(dstats, fstats, g2, be2, flag, 2);
    s3_kernel<true ><<<GRID, 256, 0, stream>>>(w3, b3, fstats, A, d_out, flag);
    s3_kernel<false><<<GRID, 256, 0, stream>>>(w3, b3, fstats, A, d_out, flag);
  } else {
    const int fti = ft ? 1 : 0;
    mlp_kernel<1,true ><<<GRID, 256, 0, stream>>>(pts,feats,ftp,fti,w1,b1,w2,b2,w3,b3,centw,gidx,dstats,fstats,d_out,flag);
    mlp_kernel<1,false><<<GRID, 256, 0, stream>>>(pts,feats,ftp,fti,w1,b1,w2,b2,w3,b3,centw,gidx,dstats,fstats,d_out,flag);
    finalize_kernel<<<1, 64, 0, stream>>>(dstats, fstats, g1, be1, flag, 1);
    mlp_kernel<2,true ><<<GRID, 256, 0, stream>>>(pts,feats,ftp,fti,w1,b1,w2,b2,w3,b3,centw,gidx,dstats,fstats,d_out,flag);
    mlp_kernel<2,false><<<GRID, 256, 0, stream>>>(pts,feats,ftp,fti,w1,b1,w2,b2,w3,b3,centw,gidx,dstats,fstats,d_out,flag);
    finalize_kernel<<<1, 64, 0, stream>>>(dstats, fstats, g2, be2, flag, 2);
    mlp_kernel<3,true ><<<GRID, 256, 0, stream>>>(pts,feats,ftp,fti,w1,b1,w2,b2,w3,b3,centw,gidx,dstats,fstats,d_out,flag);
    mlp_kernel<3,false><<<GRID, 256, 0, stream>>>(pts,feats,ftp,fti,w1,b1,w2,b2,w3,b3,centw,gidx,dstats,fstats,d_out,flag);
  }
}

// Round 8
// 1395.712 us; speedup vs baseline: 1.7868x; 1.4244x over previous
//
#include <hip/hip_runtime.h>

#define NB   16
#define NPT  4096
#define CINF 64
#define COUTF 128
#define MC   1024
#define KG   64
#define PTOT (NB*KG*MC)   /* 1048576 */

typedef unsigned short u16;
typedef unsigned int   u32;
typedef unsigned long long u64;

static __device__ __forceinline__ float blv(u16 v){ return __uint_as_float(((u32)v) << 16); }
static __device__ __forceinline__ u16 f2b(float f){
  u32 x = __float_as_uint(f);
  return (u16)((x + 0x7fffu + ((x >> 16) & 1u)) >> 16);
}

template<bool BF> struct io;
template<> struct io<true>{
  static __device__ __forceinline__ float ld(const void* p, size_t i){ return blv(((const u16*)p)[i]); }
  static __device__ __forceinline__ void st(void* p, size_t i, float v){ ((u16*)p)[i] = f2b(v); }
};
template<> struct io<false>{
  static __device__ __forceinline__ float ld(const void* p, size_t i){ return ((const float*)p)[i]; }
  static __device__ __forceinline__ void st(void* p, size_t i, float v){ ((float*)p)[i] = v; }
};

template<bool BF>
static __device__ __forceinline__ float4 ldw4(const void* w, int idx){
  if constexpr (BF) {
    ushort4 u = *(const ushort4*)((const u16*)w + idx);
    return make_float4(blv(u.x), blv(u.y), blv(u.z), blv(u.w));
  } else return *(const float4*)((const float*)w + idx);
}
template<bool BF>
static __device__ __forceinline__ void ldw8(const void* w, int idx, float4& a, float4& b){
  if constexpr (BF) {
    ushort4 u0 = *(const ushort4*)((const u16*)w + idx);
    ushort4 u1 = *(const ushort4*)((const u16*)w + idx + 4);
    a = make_float4(blv(u0.x), blv(u0.y), blv(u0.z), blv(u0.w));
    b = make_float4(blv(u1.x), blv(u1.y), blv(u1.z), blv(u1.w));
  } else {
    a = *(const float4*)((const float*)w + idx);
    b = *(const float4*)((const float*)w + idx + 4);
  }
}

// ---------------------------------------------------------------- detector + stats zero
__global__ __launch_bounds__(256) void detect_kernel(const void* pts, int* flagp, double* dstats)
{
  const int t = threadIdx.x;
  if (t < 64) {
    u32 w = ((const u32*)pts)[t];
    u64 m = __ballot((w & 0xFFFFu) < 0x4000u);
    if (t == 0) *flagp = (m == ~0ull) ? 1 : 0;
  }
  dstats[t] = 0.0;
}

// ---------------------------------------------------------------- FPS (256 thr) + fused G1 compute
template<bool BF>
static __device__ void fps_body(const void* pts, float* __restrict__ centw, void* out,
                                float* smp)
{
  float* lx = smp; float* ly = smp + NPT; float* lz = smp + 2*NPT;
  u64 (*red)[4] = (u64(*)[4])(smp + 3*NPT);
  const int t = threadIdx.x, b = blockIdx.x;
  const size_t pbase = (size_t)b*3*NPT;
  for (int i = t; i < NPT; i += 256) {
    lx[i] = io<BF>::ld(pts, pbase + i);
    ly[i] = io<BF>::ld(pts, pbase + NPT + i);
    lz[i] = io<BF>::ld(pts, pbase + 2*NPT + i);
  }
  __syncthreads();
  float qx[16],qy[16],qz[16],dd[16];
  const int base = t*16;
  #pragma unroll
  for (int j=0;j<16;++j){ qx[j]=lx[base+j]; qy[j]=ly[base+j]; qz[j]=lz[base+j]; dd[j]=1e10f; }
  int last = 0;
  const int lane = t & 63, wv = t >> 6;
  for (int it = 0; it < MC; ++it) {
    float cx = lx[last], cy = ly[last], cz = lz[last];
    if (t < 3) {
      float v = (t==0)?cx:((t==1)?cy:cz);
      centw[((size_t)b*MC + it)*3 + t] = v;
      io<BF>::st(out, (size_t)b*3*MC + (size_t)it*3 + t, v);
    }
    float bv = -1.f; int bi = base;
    #pragma unroll
    for (int j=0;j<16;++j) {
      float dx = __fsub_rn(qx[j], cx);
      float dy = __fsub_rn(qy[j], cy);
      float dz = __fsub_rn(qz[j], cz);
      float d  = __fadd_rn(__fadd_rn(__fmul_rn(dx,dx), __fmul_rn(dy,dy)), __fmul_rn(dz,dz));
      float nd = fminf(dd[j], d);
      dd[j] = nd;
      if (nd > bv) { bv = nd; bi = base + j; }   // strict >, ascending j => first max
    }
    float mv = bv;
    #pragma unroll
    for (int off = 1; off < 64; off <<= 1) mv = fmaxf(mv, __shfl_xor(mv, off, 64));
    u64 wm = __ballot(bv == mv);
    int fl = __ffsll((long long)wm) - 1;
    int wbi = __shfl(bi, fl, 64);
    if (lane == 0) red[it & 1][wv] = ((u64)__float_as_uint(mv) << 32) | (u32)(~wbi);
    __syncthreads();
    u64 k0 = red[it&1][0], k1 = red[it&1][1];
    u64 k2 = red[it&1][2], k3 = red[it&1][3];
    if (k1 > k0) k0 = k1;
    if (k3 > k2) k2 = k3;
    if (k2 > k0) k0 = k2;
    last = (int)(~(u32)k0);
  }
}

// G1[b,n,co] = sum_{c'} W1perm[c'][co] * in[n][c'] ; in = [feat0..63, px,py,pz]; no bias.
template<bool BF>
static __device__ void g1_body(const void* pts, const void* feats, const void* w1p,
                               float* __restrict__ G1, float* smp)
{
  float* Xs = smp;                       // [64][68]
  void*  w1sh = (void*)(smp + 4352);
  const int idx = blockIdx.x - NB;       // 0..1023
  const int b = idx >> 6;
  const int n0 = (idx & 63) * 64;
  const int t = threadIdx.x, lane = t & 63, wv = t >> 6;
  for (int e = t; e < 4352; e += 256) {
    int cp = e >> 6, co = e & 63;
    int src = (cp < 64) ? (co*67 + cp + 3) : (cp < 67 ? co*67 + cp - 64 : -1);
    if constexpr (BF) ((u16*)w1sh)[e]   = (src >= 0) ? ((const u16*)w1p)[src]   : (u16)0;
    else              ((float*)w1sh)[e] = (src >= 0) ? ((const float*)w1p)[src] : 0.f;
  }
  {
    float* xrow = Xs + lane*68;
    const size_t fb = ((size_t)b*CINF)*NPT + n0 + lane;
    #pragma unroll
    for (int j = 0; j < 16; ++j) {
      int c = wv*16 + j;
      xrow[c] = io<BF>::ld(feats, fb + (size_t)c*NPT);
    }
    if (wv == 0) {
      const size_t pb = (size_t)b*3*NPT + n0 + lane;
      xrow[64] = io<BF>::ld(pts, pb);
      xrow[65] = io<BF>::ld(pts, pb + NPT);
      xrow[66] = io<BF>::ld(pts, pb + 2*NPT);
      xrow[67] = 0.f;
    }
  }
  __syncthreads();
  const int kq = lane >> 4, coq = lane & 15;
  const int co0 = coq*4, k0 = wv*16 + kq*4;
  float acc[4][4];
  #pragma unroll
  for (int r=0;r<4;++r){
    #pragma unroll
    for (int j=0;j<4;++j) acc[r][j] = 0.f;
  }
  {
    const float* xb = Xs + (size_t)k0*68;
    for (int c4 = 0; c4 < 17; ++c4) {
      float4 xv[4], wr[4];
      #pragma unroll
      for (int r=0;r<4;++r) xv[r] = *(const float4*)(xb + r*68 + c4*4);
      #pragma unroll
      for (int q=0;q<4;++q) wr[q] = ldw4<BF>(w1sh, (c4*4+q)*64 + co0);
      #pragma unroll
      for (int q=0;q<4;++q){
        const float* w = (const float*)&wr[q];
        #pragma unroll
        for (int r=0;r<4;++r){
          const float x = ((const float*)&xv[r])[q];
          #pragma unroll
          for (int j=0;j<4;++j) acc[r][j] = fmaf(x, w[j], acc[r][j]);
        }
      }
    }
  }
  #pragma unroll
  for (int r=0;r<4;++r)
    *(float4*)(G1 + ((size_t)b*NPT + n0 + k0 + r)*64 + co0)
      = make_float4(acc[r][0],acc[r][1],acc[r][2],acc[r][3]);
}

__global__ __launch_bounds__(256) void fps_tr_kernel(const void* pts, const void* feats,
    const void* w1p, float* centw, float* G1, void* out, const int* flagp)
{
  __shared__ alignas(16) float smp[3*NPT + 16];
  if (blockIdx.x < NB) {
    if (*flagp) fps_body<true >(pts, centw, out, smp);
    else        fps_body<false>(pts, centw, out, smp);
  } else {
    if (*flagp) g1_body<true >(pts, feats, w1p, G1, smp);
    else        g1_body<false>(pts, feats, w1p, G1, smp);
  }
}

// ---------------------------------------------------------------- ball query
template<bool BF>
static __device__ void ballq_body(const void* pts, const float* __restrict__ centw,
                                  int* __restrict__ gidx)
{
  const int lane = threadIdx.x & 63;
  const int g = blockIdx.x*4 + (threadIdx.x >> 6);
  const int b = g >> 10;
  const size_t pbase = (size_t)b*3*NPT;
  const float cx = centw[(size_t)g*3+0], cy = centw[(size_t)g*3+1], cz = centw[(size_t)g*3+2];
  int* gout = gidx + (size_t)g*KG;
  int taken = 0, idx0 = 0;
  for (int s = 0; s < NPT; s += 64) {
    int n = s + lane;
    float dx = __fsub_rn(cx, io<BF>::ld(pts, pbase + n));
    float dy = __fsub_rn(cy, io<BF>::ld(pts, pbase + NPT + n));
    float dz = __fsub_rn(cz, io<BF>::ld(pts, pbase + 2*NPT + n));
    float d2 = __fadd_rn(__fadd_rn(__fmul_rn(dx,dx), __fmul_rn(dy,dy)), __fmul_rn(dz,dz));
    u64 mask = __ballot(d2 <= 0.04f);
    if (mask) {
      if (taken == 0) idx0 = s + __ffsll((long long)mask) - 1;
      bool win = (mask >> lane) & 1;
      int pos = taken + __popcll(mask & ((1ull << lane) - 1ull));
      if (win && pos < KG) gout[pos] = n;
      taken += (int)__popcll(mask);
      if (taken >= KG) break;
    }
  }
  int cnt = taken < KG ? taken : KG;
  if (lane >= cnt) gout[lane] = idx0;
}

__global__ __launch_bounds__(256) void ballq_kernel(const void* pts, const float* centw,
                                                    int* gidx, const int* flagp)
{
  if (*flagp) ballq_body<true >(pts, centw, gidx);
  else        ballq_body<false>(pts, centw, gidx);
}

// ================================================================ G1-GATHER PIPELINE
// conv1 out per slot = G1[gi] + d1[m],  d1[m,co] = b1[co] - W1c[co]·cent[m]

// ---------------- P1: stats1
template<bool BF>
__global__ __launch_bounds__(256) void p1_kernel(
    const void* w1p, const void* b1p,
    const float* __restrict__ centw, const int* __restrict__ gidxp,
    const float* __restrict__ G1,
    double* __restrict__ dstats, const int* __restrict__ flagp)
{
  if ((*flagp != 0) != BF) return;
  __shared__ int gids[64];
  __shared__ float d1s[64];
  __shared__ float w1cs[192];
  __shared__ float b1s[64];
  __shared__ float sbuf[128];
  const int t = threadIdx.x, lane = t & 63, cq = t >> 6;
  if (t < 64) {
    w1cs[t*3+0] = io<BF>::ld(w1p, (size_t)t*67 + 0);
    w1cs[t*3+1] = io<BF>::ld(w1p, (size_t)t*67 + 1);
    w1cs[t*3+2] = io<BF>::ld(w1p, (size_t)t*67 + 2);
    b1s[t] = io<BF>::ld(b1p, t);
  }
  const int g0 = blockIdx.x * 32;
  const int b = g0 >> 10;
  float s16[16], q16[16];
  #pragma unroll
  for (int j=0;j<16;++j){ s16[j]=0.f; q16[j]=0.f; }
  __syncthreads();
  for (int i = 0; i < 32; ++i) {
    const int g = g0 + i;
    if (t < 64) {
      gids[t] = gidxp[(size_t)g*KG + t];
      float cx = centw[(size_t)g*3], cy = centw[(size_t)g*3+1], cz = centw[(size_t)g*3+2];
      d1s[t] = b1s[t] - (w1cs[t*3]*cx + w1cs[t*3+1]*cy + w1cs[t*3+2]*cz);
    }
    __syncthreads();
    const float* row = G1 + ((size_t)b*NPT + gids[lane])*64 + cq*16;
    float vbuf[16];                                    // FIX: in-bounds array, not &v0 walk
    *(float4*)(vbuf)      = ((const float4*)row)[0];
    *(float4*)(vbuf + 4)  = ((const float4*)row)[1];
    *(float4*)(vbuf + 8)  = ((const float4*)row)[2];
    *(float4*)(vbuf + 12) = ((const float4*)row)[3];
    #pragma unroll
    for (int j=0;j<16;++j){
      float a = vbuf[j] + d1s[cq*16+j];
      s16[j] += a; q16[j] = fmaf(a, a, q16[j]);
    }
    __syncthreads();
  }
  #pragma unroll
  for (int j=0;j<16;++j){
    #pragma unroll
    for (int off = 1; off < 64; off <<= 1){
      s16[j] += __shfl_xor(s16[j], off, 64);
      q16[j] += __shfl_xor(q16[j], off, 64);
    }
  }
  if (lane == 0) {
    #pragma unroll
    for (int j=0;j<16;++j){ sbuf[cq*16+j] = s16[j]; sbuf[64+cq*16+j] = q16[j]; }
  }
  __syncthreads();
  if (t < 128) atomicAdd(&dstats[t], (double)sbuf[t]);
}

// ---------------- P2: bn1+relu (from gather) + conv2 -> stats2
template<bool BF>
__global__ __launch_bounds__(256) void p2_kernel(
    const void* w1p, const void* b1p, const void* w2p, const void* b2p,
    const float* __restrict__ fstats, double* __restrict__ dstats,
    const float* __restrict__ centw, const int* __restrict__ gidxp,
    const float* __restrict__ G1, const int* __restrict__ flagp)
{
  if ((*flagp != 0) != BF) return;
  __shared__ alignas(16) float z1[2][4352];
  __shared__ alignas(16) unsigned char w2raw[BF ? 4096*2 : 4096*4];
  __shared__ float scsh[128];
  __shared__ int gids[128];
  __shared__ float c3s[6];

  const int t = threadIdx.x, lane = t & 63, wv = t >> 6;
  const int kq = lane >> 4, coq = lane & 15;
  const int co0 = coq * 4;
  const int k0  = wv*16 + kq*4;
  const int b   = blockIdx.x >> 7;
  const int m0  = (blockIdx.x & 127) * 8;
  const int c0  = (t*4) & 63;
  const int srow = t >> 4;                 // staging row within 16-row band

  for (int e = t; e < 4096; e += 256) {
    int src = (e & 63)*64 + (e >> 6);
    if constexpr (BF) ((u16*)w2raw)[e] = ((const u16*)w2p)[src];
    else              ((float*)w2raw)[e] = ((const float*)w2p)[src];
  }
  if (t < 128) scsh[t] = fstats[t];
  float b2v[4], w1c_r[12], b1_r[4];
  #pragma unroll
  for (int j=0;j<4;++j){
    b2v[j] = io<BF>::ld(b2p, co0+j);
    b1_r[j] = io<BF>::ld(b1p, c0+j);
    #pragma unroll
    for (int i=0;i<3;++i) w1c_r[j*3+i] = io<BF>::ld(w1p, (size_t)(c0+j)*67 + i);
  }
  __syncthreads();
  float scr[4], shr[4];
  #pragma unroll
  for (int j=0;j<4;++j){ scr[j] = scsh[c0+j]; shr[j] = scsh[64+c0+j]; }
  float sp[4] = {0,0,0,0}, qp[4] = {0,0,0,0};

  for (int mo = 0; mo < 4; ++mo) {
    const size_t g0 = (size_t)b*MC + m0 + mo*2;
    if (t < 128) gids[t] = gidxp[g0*KG + t];
    if (t < 6)   c3s[t]  = centw[g0*3 + t];
    __syncthreads();
    #pragma unroll
    for (int g=0;g<2;++g){
      float d1[4];
      {
        const float cx = c3s[g*3], cy = c3s[g*3+1], cz = c3s[g*3+2];
        #pragma unroll
        for (int j=0;j<4;++j)
          d1[j] = b1_r[j] - (w1c_r[j*3]*cx + w1c_r[j*3+1]*cy + w1c_r[j*3+2]*cz);
      }
      #pragma unroll
      for (int u=0;u<4;++u){
        const int row = u*16 + srow;
        const int gi = gids[g*64 + row];
        float4 v = *(const float4*)(G1 + ((size_t)b*NPT + gi)*64 + c0);
        float4 z;
        z.x = fmaxf(0.f, fmaf(v.x + d1[0], scr[0], shr[0]));
        z.y = fmaxf(0.f, fmaf(v.y + d1[1], scr[1], shr[1]));
        z.z = fmaxf(0.f, fmaf(v.z + d1[2], scr[2], shr[2]));
        z.w = fmaxf(0.f, fmaf(v.w + d1[3], scr[3], shr[3]));
        *(float4*)(z1[g] + (size_t)row*68 + c0) = z;
      }
    }
    __syncthreads();
    float acc[2][4][4];
    #pragma unroll
    for (int g=0;g<2;++g)
      #pragma unroll
      for (int r=0;r<4;++r)
        #pragma unroll
        for (int j=0;j<4;++j) acc[g][r][j] = b2v[j];
    {
      const float* zb0 = z1[0] + (size_t)k0*68;
      const float* zb1 = z1[1] + (size_t)k0*68;
      for (int c4 = 0; c4 < 16; ++c4) {
        float4 wr[4];
        #pragma unroll
        for (int q=0;q<4;++q) wr[q] = ldw4<BF>(w2raw, (c4*4+q)*64 + co0);
        float4 xv[2][4];
        #pragma unroll
        for (int r=0;r<4;++r){ xv[0][r] = *(const float4*)(zb0 + r*68 + c4*4);
                               xv[1][r] = *(const float4*)(zb1 + r*68 + c4*4); }
        #pragma unroll
        for (int q=0;q<4;++q){
          const float* w = (const float*)&wr[q];
          #pragma unroll
          for (int g=0;g<2;++g)
            #pragma unroll
            for (int r=0;r<4;++r){
              const float x = ((const float*)&xv[g][r])[q];
              #pragma unroll
              for (int j=0;j<4;++j) acc[g][r][j] = fmaf(x, w[j], acc[g][r][j]);
            }
        }
      }
    }
    #pragma unroll
    for (int g=0;g<2;++g){
      #pragma unroll
      for (int j=0;j<4;++j){
        sp[j] += (acc[g][0][j]+acc[g][1][j]) + (acc[g][2][j]+acc[g][3][j]);
        qp[j]  = fmaf(acc[g][0][j],acc[g][0][j], fmaf(acc[g][1][j],acc[g][1][j],
                 fmaf(acc[g][2][j],acc[g][2][j], fmaf(acc[g][3][j],acc[g][3][j], qp[j]))));
      }
    }
    __syncthreads();
  }
  float* sbuf = z1[0];
  #pragma unroll
  for (int j=0;j<4;++j){ sbuf[t*4+j] = sp[j]; sbuf[1024 + t*4+j] = qp[j]; }
  __syncthreads();
  if (t < 64) {
    const int cq = t >> 2, jj = t & 3;
    float s=0.f, q=0.f;
    #pragma unroll
    for (int i=0;i<16;++i){
      const int tp = cq + 16*i;
      s += sbuf[tp*4 + jj];
      q += sbuf[1024 + tp*4 + jj];
    }
    atomicAdd(&dstats[128 + t], (double)s);
    atomicAdd(&dstats[192 + t], (double)q);
  }
}

// ---------------- P3: bn1+relu (gather) + conv2 + bn2+relu + conv3 + max -> out
template<bool BF>
__global__ __launch_bounds__(256) void p3_kernel(
    const void* w1p, const void* b1p, const void* w2p, const void* b2p,
    const void* w3p, const void* b3p,
    const float* __restrict__ fstats,
    const float* __restrict__ centw, const int* __restrict__ gidxp,
    const float* __restrict__ G1, void* out, const int* __restrict__ flagp)
{
  if ((*flagp != 0) != BF) return;
  __shared__ alignas(16) float z[4352];
  __shared__ alignas(16) unsigned char w2raw[BF ? 4096*2 : 4096*4];
  __shared__ alignas(16) unsigned char w3raw[BF ? 8192*2 : 8192*4];
  __shared__ float scsh[256];
  __shared__ int gids[64];
  __shared__ float c3s[3];

  const int t = threadIdx.x, lane = t & 63, wv = t >> 6;
  const int kq = lane >> 4, coq = lane & 15;
  const int co0 = coq * 4;
  const int co08 = coq * 8;
  const int k0  = wv*16 + kq*4;
  const int b   = blockIdx.x >> 7;
  const int m0  = (blockIdx.x & 127) * 8;
  const int c0  = (t*4) & 63;
  const int srow = t >> 4;

  for (int e = t; e < 4096; e += 256) {
    int src = (e & 63)*64 + (e >> 6);
    if constexpr (BF) ((u16*)w2raw)[e] = ((const u16*)w2p)[src];
    else              ((float*)w2raw)[e] = ((const float*)w2p)[src];
  }
  for (int e = t; e < 8192; e += 256) {
    int src = (e & 127)*64 + (e >> 7);
    if constexpr (BF) ((u16*)w3raw)[e] = ((const u16*)w3p)[src];
    else              ((float*)w3raw)[e] = ((const float*)w3p)[src];
  }
  scsh[t] = fstats[t];
  float b2v[4], b3v[8], w1c_r[12], b1_r[4];
  #pragma unroll
  for (int j=0;j<4;++j){
    b2v[j] = io<BF>::ld(b2p, co0+j);
    b1_r[j] = io<BF>::ld(b1p, c0+j);
    #pragma unroll
    for (int i=0;i<3;++i) w1c_r[j*3+i] = io<BF>::ld(w1p, (size_t)(c0+j)*67 + i);
  }
  #pragma unroll
  for (int j=0;j<8;++j) b3v[j] = io<BF>::ld(b3p, co08+j);
  __syncthreads();
  float scr[4], shr[4], sc2[4], sh2[4];
  #pragma unroll
  for (int j=0;j<4;++j){
    scr[j] = scsh[c0+j];  shr[j] = scsh[64+c0+j];
    sc2[j] = scsh[128+co0+j]; sh2[j] = scsh[192+co0+j];
  }
  float outv[8];

  for (int mi = 0; mi < 8; ++mi) {
    const size_t g = (size_t)b*MC + m0 + mi;
    if (t < 64) gids[t] = gidxp[g*KG + t];
    if (t < 3)  c3s[t]  = centw[g*3 + t];
    __syncthreads();
    {
      float d1[4];
      const float cx = c3s[0], cy = c3s[1], cz = c3s[2];
      #pragma unroll
      for (int j=0;j<4;++j)
        d1[j] = b1_r[j] - (w1c_r[j*3]*cx + w1c_r[j*3+1]*cy + w1c_r[j*3+2]*cz);
      #pragma unroll
      for (int u=0;u<4;++u){
        const int row = u*16 + srow;
        const int gi = gids[row];
        float4 v = *(const float4*)(G1 + ((size_t)b*NPT + gi)*64 + c0);
        float4 zz;
        zz.x = fmaxf(0.f, fmaf(v.x + d1[0], scr[0], shr[0]));
        zz.y = fmaxf(0.f, fmaf(v.y + d1[1], scr[1], shr[1]));
        zz.z = fmaxf(0.f, fmaf(v.z + d1[2], scr[2], shr[2]));
        zz.w = fmaxf(0.f, fmaf(v.w + d1[3], scr[3], shr[3]));
        *(float4*)(z + (size_t)row*68 + c0) = zz;
      }
    }
    __syncthreads();
    // conv2 -> regs
    float acc2[4][4];
    #pragma unroll
    for (int r=0;r<4;++r){
      #pragma unroll
      for (int j=0;j<4;++j) acc2[r][j] = b2v[j];
    }
    {
      const float* zb = z + (size_t)k0*68;
      for (int c4 = 0; c4 < 16; ++c4) {
        float4 xv[4], wr[4];
        #pragma unroll
        for (int r=0;r<4;++r) xv[r] = *(const float4*)(zb + r*68 + c4*4);
        #pragma unroll
        for (int q=0;q<4;++q) wr[q] = ldw4<BF>(w2raw, (c4*4+q)*64 + co0);
        #pragma unroll
        for (int q=0;q<4;++q){
          const float* w = (const float*)&wr[q];
          #pragma unroll
          for (int r=0;r<4;++r){
            const float x = ((const float*)&xv[r])[q];
            #pragma unroll
            for (int j=0;j<4;++j) acc2[r][j] = fmaf(x, w[j], acc2[r][j]);
          }
        }
      }
    }
    __syncthreads();   // z (z1) reads done before overwrite
    // bn2+relu -> z
    #pragma unroll
    for (int r=0;r<4;++r){
      float4 zv;
      zv.x = fmaxf(0.f, fmaf(acc2[r][0], sc2[0], sh2[0]));
      zv.y = fmaxf(0.f, fmaf(acc2[r][1], sc2[1], sh2[1]));
      zv.z = fmaxf(0.f, fmaf(acc2[r][2], sc2[2], sh2[2]));
      zv.w = fmaxf(0.f, fmaf(acc2[r][3], sc2[3], sh2[3]));
      *(float4*)(z + (size_t)(k0+r)*68 + co0) = zv;
    }
    __syncthreads();
    // conv3
    float a3[4][8];
    #pragma unroll
    for (int r=0;r<4;++r){
      #pragma unroll
      for (int j=0;j<8;++j) a3[r][j] = b3v[j];
    }
    {
      const float* zb = z + (size_t)k0*68;
      for (int c4 = 0; c4 < 16; ++c4) {
        float4 xv[4], wr[4][2];
        #pragma unroll
        for (int r=0;r<4;++r) xv[r] = *(const float4*)(zb + r*68 + c4*4);
        #pragma unroll
        for (int q=0;q<4;++q) ldw8<BF>(w3raw, (c4*4+q)*128 + co08, wr[q][0], wr[q][1]);
        #pragma unroll
        for (int q=0;q<4;++q){
          const float* w = (const float*)&wr[q][0];
          #pragma unroll
          for (int r=0;r<4;++r){
            const float x = ((const float*)&xv[r])[q];
            #pragma unroll
            for (int j=0;j<8;++j) a3[r][j] = fmaf(x, w[j], a3[r][j]);
          }
        }
      }
    }
    __syncthreads();   // z (z2) reads done before redm overlays
    float* redm = z;
    #pragma unroll
    for (int j=0;j<8;++j){
      float mv = fmaxf(fmaxf(a3[0][j],a3[1][j]), fmaxf(a3[2][j],a3[3][j]));
      redm[(co08+j)*17 + wv*4 + kq] = mv;
    }
    __syncthreads();
    if (t < 128) {
      const float* rr = redm + t*17;
      float s = rr[0];
      #pragma unroll
      for (int i=1;i<16;++i) s = fmaxf(s, rr[i]);
      outv[mi] = s;
    }
    __syncthreads();   // redm reads done before next staging overwrites z
  }
  if (t < 128) {
    const size_t obase = (size_t)NB*3*MC + ((size_t)b*COUTF + t)*MC + m0;
    if (BF) {
      uint4 v;
      v.x = (u32)f2b(outv[0]) | ((u32)f2b(outv[1]) << 16);
      v.y = (u32)f2b(outv[2]) | ((u32)f2b(outv[3]) << 16);
      v.z = (u32)f2b(outv[4]) | ((u32)f2b(outv[5]) << 16);
      v.w = (u32)f2b(outv[6]) | ((u32)f2b(outv[7]) << 16);
      *(uint4*)((u16*)out + obase) = v;
    } else {
      float* op = (float*)out + obase;
      *(float4*)(op)     = make_float4(outv[0],outv[1],outv[2],outv[3]);
      *(float4*)(op + 4) = make_float4(outv[4],outv[5],outv[6],outv[7]);
    }
  }
}

// ================================================================ FALLBACK (tiny-ws): fused, ft=0
template<int STAGE, bool BF>
__global__ __launch_bounds__(256) void mlp_kernel(
    const void* pts, const void* feats,
    const void* w1p, const void* b1p, const void* w2p, const void* b2p,
    const void* w3p, const void* b3p,
    const float* __restrict__ centw, const int* __restrict__ gidxp,
    double* __restrict__ dstats, const float* __restrict__ fstats, void* out,
    const int* __restrict__ flagp)
{
  if ((*flagp != 0) != BF) return;
  constexpr int ACTF = 4352 + (STAGE>=2 ? 4352 : 0);
  constexpr int W1B  = BF ? 4352*2 : 4352*4;
  constexpr int W2B  = (STAGE>=2) ? (BF ? 4096*2 : 4096*4) : 0;
  constexpr int W3B  = (STAGE==3) ? (BF ? 8192*2 : 8192*4) : 0;
  constexpr int REDB = (STAGE==1) ? 8704 : 0;
  constexpr int SMB  = ACTF*4 + W1B + W2B + W3B + REDB;
  __shared__ alignas(16) unsigned char smem[SMB];
  __shared__ int gids[64];
  __shared__ float c3s[3];
  float* Xs  = (float*)smem;
  float* z1s = Xs + 4352;
  void*  w1t = smem + ACTF*4;
  void*  w2t = smem + ACTF*4 + W1B;
  void*  w3t = smem + ACTF*4 + W1B + W2B;
  float* red = (STAGE==1) ? (float*)(smem + ACTF*4 + W1B) : z1s;
  const int t = threadIdx.x, lane = t & 63, wv = t >> 6;
  const int kq = lane >> 4, coq = lane & 15;
  const int co0 = coq * 4, co08 = coq * 8;
  const int k0  = wv*16 + kq*4;
  const int b   = blockIdx.x >> 7;
  const int m0  = (blockIdx.x & 127) * 8;
  for (int e = t; e < 4352; e += 256) {
    int cp = e >> 6, co = e & 63;
    int src = (cp < 64) ? (co*67 + cp + 3) : (cp < 67 ? co*67 + cp - 64 : -1);
    if constexpr (BF) ((u16*)w1t)[e]  = (src >= 0) ? ((const u16*)w1p)[src]  : (u16)0;
    else              ((float*)w1t)[e] = (src >= 0) ? ((const float*)w1p)[src] : 0.f;
  }
  if constexpr (STAGE >= 2)
    for (int e = t; e < 4096; e += 256) {
      int src = (e & 63)*64 + (e >> 6);
      if constexpr (BF) ((u16*)w2t)[e] = ((const u16*)w2p)[src];
      else              ((float*)w2t)[e] = ((const float*)w2p)[src];
    }
  if constexpr (STAGE == 3)
    for (int e = t; e < 8192; e += 256) {
      int src = (e & 127)*64 + (e >> 7);
      if constexpr (BF) ((u16*)w3t)[e] = ((const u16*)w3p)[src];
      else              ((float*)w3t)[e] = ((const float*)w3p)[src];
    }
  float b1v[4], b2v[4], sc1v[4], sh1v[4], sc2v[4], sh2v[4], b3v[8];
  #pragma unroll
  for (int j=0;j<4;++j) b1v[j] = io<BF>::ld(b1p, co0+j);
  if constexpr (STAGE >= 2) {
    #pragma unroll
    for (int j=0;j<4;++j) {
      b2v[j]  = io<BF>::ld(b2p, co0+j);
      sc1v[j] = fstats[co0+j]; sh1v[j] = fstats[64+co0+j];
    }
  }
  if constexpr (STAGE == 3) {
    #pragma unroll
    for (int j=0;j<4;++j) { sc2v[j] = fstats[128+co0+j]; sh2v[j] = fstats[192+co0+j]; }
    #pragma unroll
    for (int j=0;j<8;++j) b3v[j] = io<BF>::ld(b3p, co08+j);
  }
  float run_s = 0.f, run_q = 0.f;
  float outv[8];
  __syncthreads();
  for (int mi = 0; mi < 8; ++mi) {
    const int m = m0 + mi;
    const size_t g = (size_t)b*MC + m;
    if (t < 64) gids[t] = gidxp[g*KG + t];
    if (t < 3)  c3s[t]  = centw[g*3 + t];
    __syncthreads();
    {
      const int gi = gids[lane];
      float* xrow = Xs + lane*68;
      const int cs = wv*16;
      for (int c = cs; c < cs+16; ++c)
        xrow[c] = io<BF>::ld(feats, ((size_t)b*CINF + c)*NPT + gi);
      if (wv == 0) {
        const size_t pbase = (size_t)b*3*NPT;
        xrow[64] = __fsub_rn(io<BF>::ld(pts, pbase + gi),         c3s[0]);
        xrow[65] = __fsub_rn(io<BF>::ld(pts, pbase + NPT + gi),   c3s[1]);
        xrow[66] = __fsub_rn(io<BF>::ld(pts, pbase + 2*NPT + gi), c3s[2]);
        xrow[67] = 0.f;
      }
    }
    __syncthreads();
    float acc[4][4];
    #pragma unroll
    for (int r=0;r<4;++r){
      #pragma unroll
      for (int j=0;j<4;++j) acc[r][j] = b1v[j];
    }
    {
      const float* xb = Xs + (size_t)k0*68;
      for (int c4 = 0; c4 < 17; ++c4) {
        float4 xv[4], wr[4];
        #pragma unroll
        for (int r=0;r<4;++r) xv[r] = *(const float4*)(xb + r*68 + c4*4);
        #pragma unroll
        for (int q=0;q<4;++q) wr[q] = ldw4<BF>(w1t, (c4*4+q)*64 + co0);
        #pragma unroll
        for (int q=0;q<4;++q){
          const float* w = (const float*)&wr[q];
          #pragma unroll
          for (int r=0;r<4;++r){
            const float x = ((const float*)&xv[r])[q];
            #pragma unroll
            for (int j=0;j<4;++j) acc[r][j] = fmaf(x, w[j], acc[r][j]);
          }
        }
      }
    }
    if constexpr (STAGE == 1) {
      #pragma unroll
      for (int j=0;j<4;++j){
        float s  = (acc[0][j]+acc[1][j]) + (acc[2][j]+acc[3][j]);
        float q2 = fmaf(acc[0][j],acc[0][j], fmaf(acc[1][j],acc[1][j],
                   fmaf(acc[2][j],acc[2][j], acc[3][j]*acc[3][j])));
        red[(co0+j)*17 + wv*4 + kq] = s;
        red[1088 + (co0+j)*17 + wv*4 + kq] = q2;
      }
      __syncthreads();
      if (t < 64) {
        const float* r1 = red + t*17; const float* r2 = red + 1088 + t*17;
        float s=0.f, q=0.f;
        #pragma unroll
        for (int i=0;i<16;++i){ s += r1[i]; q += r2[i]; }
        run_s += s; run_q += q;
      }
    } else {
      #pragma unroll
      for (int r=0;r<4;++r){
        float4 zv;
        zv.x = fmaxf(0.f, fmaf(acc[r][0], sc1v[0], sh1v[0]));
        zv.y = fmaxf(0.f, fmaf(acc[r][1], sc1v[1], sh1v[1]));
        zv.z = fmaxf(0.f, fmaf(acc[r][2], sc1v[2], sh1v[2]));
        zv.w = fmaxf(0.f, fmaf(acc[r][3], sc1v[3], sh1v[3]));
        *(float4*)(z1s + (size_t)(k0+r)*68 + co0) = zv;
      }
      __syncthreads();
      float acc2[4][4];
      #pragma unroll
      for (int r=0;r<4;++r){
        #pragma unroll
        for (int j=0;j<4;++j) acc2[r][j] = b2v[j];
      }
      {
        const float* zb = z1s + (size_t)k0*68;
        for (int c4 = 0; c4 < 16; ++c4) {
          float4 xv[4], wr[4];
          #pragma unroll
          for (int r=0;r<4;++r) xv[r] = *(const float4*)(zb + r*68 + c4*4);
          #pragma unroll
          for (int q=0;q<4;++q) wr[q] = ldw4<BF>(w2t, (c4*4+q)*64 + co0);
          #pragma unroll
          for (int q=0;q<4;++q){
            const float* w = (const float*)&wr[q];
            #pragma unroll
            for (int r=0;r<4;++r){
              const float x = ((const float*)&xv[r])[q];
              #pragma unroll
              for (int j=0;j<4;++j) acc2[r][j] = fmaf(x, w[j], acc2[r][j]);
            }
          }
        }
      }
      if constexpr (STAGE == 2) {
        __syncthreads();
        #pragma unroll
        for (int j=0;j<4;++j){
          float s  = (acc2[0][j]+acc2[1][j]) + (acc2[2][j]+acc2[3][j]);
          float q2 = fmaf(acc2[0][j],acc2[0][j], fmaf(acc2[1][j],acc2[1][j],
                     fmaf(acc2[2][j],acc2[2][j], acc2[3][j]*acc2[3][j])));
          red[(co0+j)*17 + wv*4 + kq] = s;
          red[1088 + (co0+j)*17 + wv*4 + kq] = q2;
        }
        __syncthreads();
        if (t < 64) {
          const float* r1 = red + t*17; const float* r2 = red + 1088 + t*17;
          float s=0.f, q=0.f;
          #pragma unroll
          for (int i=0;i<16;++i){ s += r1[i]; q += r2[i]; }
          run_s += s; run_q += q;
        }
      } else {
        #pragma unroll
        for (int r=0;r<4;++r){
          float4 zv;
          zv.x = fmaxf(0.f, fmaf(acc2[r][0], sc2v[0], sh2v[0]));
          zv.y = fmaxf(0.f, fmaf(acc2[r][1], sc2v[1], sh2v[1]));
          zv.z = fmaxf(0.f, fmaf(acc2[r][2], sc2v[2], sh2v[2]));
          zv.w = fmaxf(0.f, fmaf(acc2[r][3], sc2v[3], sh2v[3]));
          *(float4*)(Xs + (size_t)(k0+r)*68 + co0) = zv;
        }
        __syncthreads();
        float a3[4][8];
        #pragma unroll
        for (int r=0;r<4;++r){
          #pragma unroll
          for (int j=0;j<8;++j) a3[r][j] = b3v[j];
        }
        {
          const float* zb = Xs + (size_t)k0*68;
          for (int c4 = 0; c4 < 16; ++c4) {
            float4 xv[4], wr[4][2];
            #pragma unroll
            for (int r=0;r<4;++r) xv[r] = *(const float4*)(zb + r*68 + c4*4);
            #pragma unroll
            for (int q=0;q<4;++q) ldw8<BF>(w3t, (c4*4+q)*128 + co08, wr[q][0], wr[q][1]);
            #pragma unroll
            for (int q=0;q<4;++q){
              const float* w = (const float*)&wr[q][0];
              #pragma unroll
              for (int r=0;r<4;++r){
                const float x = ((const float*)&xv[r])[q];
                #pragma unroll
                for (int j=0;j<8;++j) a3[r][j] = fmaf(x, w[j], a3[r][j]);
              }
            }
          }
        }
        float* redm = red;
        #pragma unroll
        for (int j=0;j<8;++j){
          float mv = fmaxf(fmaxf(a3[0][j],a3[1][j]), fmaxf(a3[2][j],a3[3][j]));
          redm[(co08+j)*17 + wv*4 + kq] = mv;
        }
        __syncthreads();
        if (t < 128) {
          const float* rr = redm + t*17;
          float s = rr[0];
          #pragma unroll
          for (int i=1;i<16;++i) s = fmaxf(s, rr[i]);
          outv[mi] = s;
        }
      }
    }
  }
  if constexpr (STAGE <= 2) {
    if (t < 64) {
      atomicAdd(&dstats[(STAGE==1 ? 0 : 128) + lane], (double)run_s);
      atomicAdd(&dstats[(STAGE==1 ? 64 : 192) + lane], (double)run_q);
    }
  } else {
    if (t < 128) {
      const size_t obase = (size_t)NB*3*MC + ((size_t)b*COUTF + t)*MC + m0;
      if (BF) {
        uint4 v;
        v.x = (u32)f2b(outv[0]) | ((u32)f2b(outv[1]) << 16);
        v.y = (u32)f2b(outv[2]) | ((u32)f2b(outv[3]) << 16);
        v.z = (u32)f2b(outv[4]) | ((u32)f2b(outv[5]) << 16);
        v.w = (u32)f2b(outv[6]) | ((u32)f2b(outv[7]) << 16);
        *(uint4*)((u16*)out + obase) = v;
      } else {
        float* op = (float*)out + obase;
        *(float4*)(op)     = make_float4(outv[0],outv[1],outv[2],outv[3]);
        *(float4*)(op + 4) = make_float4(outv[4],outv[5],outv[6],outv[7]);
      }
    }
  }
}

// ---------------------------------------------------------------- BN finalize
__global__ void finalize_kernel(const double* __restrict__ dstats, float* __restrict__ fstats,
                                const void* g, const void* beta, const int* flagp, int stage)
{
  const int t = threadIdx.x;   // 64
  const int off = (stage==1) ? 0 : 128;
  const double inv = 1.0 / (double)PTOT;
  double mu = dstats[off + t] * inv;
  double q  = dstats[off + 64 + t] * inv;
  double var = q - mu*mu;
  if (var < 0.0) var = 0.0;
  float gg, bb;
  if (*flagp) { gg = blv(((const u16*)g)[t]);  bb = blv(((const u16*)beta)[t]); }
  else        { gg = ((const float*)g)[t];     bb = ((const float*)beta)[t]; }
  double scale = (double)gg / sqrt(var + 1e-5);
  fstats[off + t]      = (float)scale;
  fstats[off + 64 + t] = bb - (float)(mu*scale);
}

// ---------------------------------------------------------------- host
extern "C" void kernel_launch(void* const* d_in, const int* in_sizes, int n_in,
                              void* d_out, int out_size, void* d_ws, size_t ws_size,
                              hipStream_t stream)
{
  (void)in_sizes; (void)n_in; (void)out_size;
  const void* pts  = d_in[0];
  const void* feats= d_in[1];
  const void* w1   = d_in[2];
  const void* b1   = d_in[3];
  const void* g1   = d_in[4];
  const void* be1  = d_in[5];
  const void* w2   = d_in[6];
  const void* b2   = d_in[7];
  const void* g2   = d_in[8];
  const void* be2  = d_in[9];
  const void* w3   = d_in[10];
  const void* b3   = d_in[11];

  char* ws = (char*)d_ws;
  int*    flag   = (int*)ws;
  double* dstats = (double*)(ws + 64);
  float*  fstats = (float*)(ws + 2112);
  float*  centw  = (float*)(ws + 4096);
  int*    gidx   = (int*)(ws + 200704);
  float*  G1     = (float*)(ws + 4395008);
  const bool gpath = ws_size >= 21172224ull;

  detect_kernel<<<1, 256, 0, stream>>>(pts, flag, dstats);
  fps_tr_kernel<<<gpath ? (NB + NB*NPT/64) : NB, 256, 0, stream>>>(pts, feats, w1, centw, G1, d_out, flag);
  ballq_kernel<<<NB*MC/4, 256, 0, stream>>>(pts, centw, gidx, flag);

  if (gpath) {
    p1_kernel<true ><<<NB*MC/32, 256, 0, stream>>>(w1, b1, centw, gidx, G1, dstats, flag);
    p1_kernel<false><<<NB*MC/32, 256, 0, stream>>>(w1, b1, centw, gidx, G1, dstats, flag);
    finalize_kernel<<<1, 64, 0, stream>>>(dstats, fstats, g1, be1, flag, 1);
    p2_kernel<true ><<<NB*MC/8, 256, 0, stream>>>(w1, b1, w2, b2, fstats, dstats, centw, gidx, G1, flag);
    p2_kernel<false><<<NB*MC/8, 256, 0, stream>>>(w1, b1, w2, b2, fstats, dstats, centw, gidx, G1, flag);
    finalize_kernel<<<1, 64, 0, stream>>>(dstats, fstats, g2, be2, flag, 2);
    p3_kernel<true ><<<NB*MC/8, 256, 0, stream>>>(w1, b1, w2, b2, w3, b3, fstats, centw, gidx, G1, d_out, flag);
    p3_kernel<false><<<NB*MC/8, 256, 0, stream>>>(w1, b1, w2, b2, w3, b3, fstats, centw, gidx, G1, d_out, flag);
  } else {
    const int GRID = NB*MC/8;
    mlp_kernel<1,true ><<<GRID, 256, 0, stream>>>(pts,feats,w1,b1,w2,b2,w3,b3,centw,gidx,dstats,fstats,d_out,flag);
    mlp_kernel<1,false><<<GRID, 256, 0, stream>>>(pts,feats,w1,b1,w2,b2,w3,b3,centw,gidx,dstats,fstats,d_out,flag);
    finalize_kernel<<<1, 64, 0, stream>>>(dstats, fstats, g1, be1, flag, 1);
    mlp_kernel<2,true ><<<GRID, 256, 0, stream>>>(pts,feats,w1,b1,w2,b2,w3,b3,centw,gidx,dstats,fstats,d_out,flag);
    mlp_kernel<2,false><<<GRID, 256, 0, stream>>>(pts,feats,w1,b1,w2,b2,w3,b3,centw,gidx,dstats,fstats,d_out,flag);
    finalize_kernel<<<1, 64, 0, stream>>>(dstats, fstats, g2, be2, flag, 2);
    mlp_kernel<3,true ><<<GRID, 256, 0, stream>>>(pts,feats,w1,b1,w2,b2,w3,b3,centw,gidx,dstats,fstats,d_out,flag);
    mlp_kernel<3,false><<<GRID, 256, 0, stream>>>(pts,feats,w1,b1,w2,b2,w3,b3,centw,gidx,dstats,fstats,d_out,flag);
  }
}